// Round 1
// baseline (2565.593 us; speedup 1.0000x reference)
//
#include <hip/hip_runtime.h>

// Problem constants (from reference)
#define SN 50000
#define EN 20000
#define KN 128
#define DN 64
#define BN 4096
#define NE 1000000
#define NLAYER 3

__device__ __forceinline__ float sigmoidf_(float v) { return 1.f / (1.f + __expf(-v)); }

// ---------------------------------------------------------------------------
// CSR build
// ---------------------------------------------------------------------------
__global__ __launch_bounds__(256) void count_kernel(const int* __restrict__ rows,
                                                    int* __restrict__ cnt, int ne) {
    int i = blockIdx.x * 256 + threadIdx.x;
    if (i < ne) atomicAdd(&cnt[rows[i]], 1);
}

__global__ __launch_bounds__(1024) void exscan_kernel(const int* __restrict__ cnt,
                                                      int* __restrict__ rp, int n) {
    __shared__ int part[1024];
    const int t = threadIdx.x;
    const int chunk = (n + 1023) / 1024;
    const int beg = t * chunk;
    const int end = min(beg + chunk, n);
    int s = 0;
    for (int i = beg; i < end; ++i) s += cnt[i];
    part[t] = s;
    __syncthreads();
    for (int off = 1; off < 1024; off <<= 1) {
        int v = part[t];
        int u = (t >= off) ? part[t - off] : 0;
        __syncthreads();
        part[t] = v + u;
        __syncthreads();
    }
    int prefix = (t == 0) ? 0 : part[t - 1];
    for (int i = beg; i < end; ++i) { rp[i] = prefix; prefix += cnt[i]; }
    if (t == 1023) rp[n] = part[1023];
}

__global__ __launch_bounds__(256) void fill_kernel(const int* __restrict__ rows,
                                                   const int* __restrict__ cols,
                                                   const float* __restrict__ vals,
                                                   int* __restrict__ cursor,
                                                   int* __restrict__ cs,
                                                   float* __restrict__ vs, int ne) {
    int i = blockIdx.x * 256 + threadIdx.x;
    if (i < ne) {
        int r = rows[i];
        int p = atomicAdd(&cursor[r], 1);
        cs[p] = cols[i];
        vs[p] = vals[i];
    }
}

// ---------------------------------------------------------------------------
// Generic tiled GEMM: out[M,NCOLS] = act( X[M,KK] @ (maybe-abs W[NCOLS,KK])^T + bias )
// ---------------------------------------------------------------------------
template <int KK, int NCOLS, int ROWS, bool ABSW, bool SIG>
__global__ __launch_bounds__(256) void gemm_xwT(const float* __restrict__ X,
                                                const float* __restrict__ W,
                                                const float* __restrict__ bias,
                                                float* __restrict__ out, int M) {
    constexpr int KP = 32;            // k-phase size
    constexpr int NG = 256 / NCOLS;   // row groups per block
    constexpr int RT = ROWS / NG;     // rows per thread (==16 for all instantiations)
    __shared__ float BT[KP * (NCOLS + 1)];
    __shared__ float Xl[ROWS * (KK + 1)];
    const int t = threadIdx.x;
    const int j = t % NCOLS;
    const int rg = t / NCOLS;
    const int row0 = blockIdx.x * ROWS;

    for (int idx = t; idx < ROWS * KK; idx += 256) {
        int r = idx / KK, k = idx % KK;
        int gr = row0 + r;
        Xl[r * (KK + 1) + k] = (gr < M) ? X[gr * KK + k] : 0.f;
    }
    float acc[RT];
#pragma unroll
    for (int i = 0; i < RT; ++i) acc[i] = 0.f;

    for (int k0 = 0; k0 < KK; k0 += KP) {
        __syncthreads();
        for (int idx = t; idx < NCOLS * KP; idx += 256) {
            int jj = idx / KP, kp = idx % KP;
            float w = W[jj * KK + k0 + kp];
            BT[kp * (NCOLS + 1) + jj] = ABSW ? fabsf(w) : w;
        }
        __syncthreads();
#pragma unroll
        for (int kp = 0; kp < KP; ++kp) {
            float b = BT[kp * (NCOLS + 1) + j];
#pragma unroll
            for (int rr = 0; rr < RT; ++rr)
                acc[rr] += Xl[(rg * RT + rr) * (KK + 1) + k0 + kp] * b;
        }
    }
    float bj = bias ? bias[j] : 0.f;
#pragma unroll
    for (int rr = 0; rr < RT; ++rr) {
        int gr = row0 + rg * RT + rr;
        if (gr < M) {
            float v = acc[rr] + bj;
            out[gr * NCOLS + j] = SIG ? sigmoidf_(v) : v;
        }
    }
}

// ---------------------------------------------------------------------------
// Fused SPMM: out = A1 (x) g1 + A0 (x) g0 + dA.*yA + dB.*yB + (b1+b0)
// wave per row, lane l owns columns l and l+64
// ---------------------------------------------------------------------------
__global__ __launch_bounds__(256) void spmm_fused(
    const int* __restrict__ rp1, const int* __restrict__ c1, const float* __restrict__ v1,
    const float* __restrict__ g1,
    const int* __restrict__ rp0, const int* __restrict__ c0, const float* __restrict__ v0,
    const float* __restrict__ g0,
    const float* __restrict__ dA, const float* __restrict__ dB,
    const float* __restrict__ yA, const float* __restrict__ yB,
    const float* __restrict__ b1, const float* __restrict__ b0,
    float* __restrict__ out, int nrows) {
    const int wave = (blockIdx.x * 256 + threadIdx.x) >> 6;
    const int lane = threadIdx.x & 63;
    if (wave >= nrows) return;
    const int r = wave;
    float acc0 = 0.f, acc1 = 0.f;

    {
        int e = rp1[r], eend = rp1[r + 1];
        for (; e + 4 <= eend; e += 4) {
            int ca = c1[e], cb = c1[e + 1], cc = c1[e + 2], cd = c1[e + 3];
            float va = v1[e], vb = v1[e + 1], vc = v1[e + 2], vd = v1[e + 3];
            float a0 = g1[(ca << 7) + lane],      a1 = g1[(ca << 7) + 64 + lane];
            float b0v = g1[(cb << 7) + lane],     b1v = g1[(cb << 7) + 64 + lane];
            float c0v = g1[(cc << 7) + lane],     c1v = g1[(cc << 7) + 64 + lane];
            float d0v = g1[(cd << 7) + lane],     d1v = g1[(cd << 7) + 64 + lane];
            acc0 += va * a0 + vb * b0v + vc * c0v + vd * d0v;
            acc1 += va * a1 + vb * b1v + vc * c1v + vd * d1v;
        }
        for (; e < eend; ++e) {
            int c = c1[e]; float v = v1[e];
            acc0 += v * g1[(c << 7) + lane];
            acc1 += v * g1[(c << 7) + 64 + lane];
        }
    }
    {
        int e = rp0[r], eend = rp0[r + 1];
        for (; e + 4 <= eend; e += 4) {
            int ca = c0[e], cb = c0[e + 1], cc = c0[e + 2], cd = c0[e + 3];
            float va = v0[e], vb = v0[e + 1], vc = v0[e + 2], vd = v0[e + 3];
            float a0 = g0[(ca << 7) + lane],      a1 = g0[(ca << 7) + 64 + lane];
            float b0v = g0[(cb << 7) + lane],     b1v = g0[(cb << 7) + 64 + lane];
            float c0v = g0[(cc << 7) + lane],     c1v = g0[(cc << 7) + 64 + lane];
            float d0v = g0[(cd << 7) + lane],     d1v = g0[(cd << 7) + 64 + lane];
            acc0 += va * a0 + vb * b0v + vc * c0v + vd * d0v;
            acc1 += va * a1 + vb * b1v + vc * c1v + vd * d1v;
        }
        for (; e < eend; ++e) {
            int c = c0[e]; float v = v0[e];
            acc0 += v * g0[(c << 7) + lane];
            acc1 += v * g0[(c << 7) + 64 + lane];
        }
    }
    const float da = dA[r], db = dB[r];
    const int base = r << 7;
    acc0 += da * yA[base + lane] + db * yB[base + lane] + b1[lane] + b0[lane];
    acc1 += da * yA[base + 64 + lane] + db * yB[base + 64 + lane] + b1[64 + lane] + b0[64 + lane];
    out[base + lane] = acc0;
    out[base + 64 + lane] = acc1;
}

// ---------------------------------------------------------------------------
// Head kernels
// ---------------------------------------------------------------------------
__global__ __launch_bounds__(128) void head1_kernel(
    const int* __restrict__ stu_id, const int* __restrict__ exer_id,
    const float* __restrict__ kn_emb, const float* __restrict__ stat,
    const float* __restrict__ kdiff, const float* __restrict__ stu_bias,
    const float* __restrict__ e_disc, float* __restrict__ x) {
    const int b = blockIdx.x;
    const int k = threadIdx.x;
    const int sid = stu_id[b], eid = exer_id[b];
    float disc = sigmoidf_(e_disc[eid]);
    float sb = sigmoidf_(stat[(sid << 7) + k] + stu_bias[sid]);
    float kd = sigmoidf_(kdiff[(eid << 7) + k]);
    x[(b << 7) + k] = disc * (sb - kd) * kn_emb[(b << 7) + k];
}

__global__ __launch_bounds__(256) void pn3_kernel(const float* __restrict__ h2,
                                                  const float* __restrict__ w3,
                                                  const float* __restrict__ b3,
                                                  float* __restrict__ out) {
    __shared__ float wl[128];
    const int t = threadIdx.x;
    if (t < 128) wl[t] = fabsf(w3[t]);
    __syncthreads();
    const int b = blockIdx.x * 256 + t;
    float acc = 0.f;
#pragma unroll 4
    for (int k = 0; k < 128; ++k) acc += h2[(b << 7) + k] * wl[k];
    out[b] = sigmoidf_(acc + b3[0]);
}

// ---------------------------------------------------------------------------
// Launch
// ---------------------------------------------------------------------------
static inline size_t align256(size_t x) { return (x + 255) & ~size_t(255); }

extern "C" void kernel_launch(void* const* d_in, const int* in_sizes, int n_in,
                              void* d_out, int out_size, void* d_ws, size_t ws_size,
                              hipStream_t stream) {
    const int*   stu_id   = (const int*)d_in[0];
    const int*   exer_id  = (const int*)d_in[1];
    const float* kn_emb   = (const float*)d_in[2];
    const float* stu_emb  = (const float*)d_in[3];
    const float* exer_emb = (const float*)d_in[4];
    const float* kn_base  = (const float*)d_in[5];
    const float* stu_bias = (const float*)d_in[6];
    const float* e_disc   = (const float*)d_in[7];
    const float* W1_w     = (const float*)d_in[8];
    const float* W1_b     = (const float*)d_in[9];
    const float* W0_w     = (const float*)d_in[10];
    const float* W0_b     = (const float*)d_in[11];
    const float* pn1_w    = (const float*)d_in[12];
    const float* pn1_b    = (const float*)d_in[13];
    const float* pn2_w    = (const float*)d_in[14];
    const float* pn2_b    = (const float*)d_in[15];
    const float* pn3_w    = (const float*)d_in[16];
    const float* pn3_b    = (const float*)d_in[17];
    const int*   ui1_r = (const int*)d_in[18]; const int* ui1_c = (const int*)d_in[19];
    const float* ui1_v = (const float*)d_in[20];
    const int*   iu1_r = (const int*)d_in[21]; const int* iu1_c = (const int*)d_in[22];
    const float* iu1_v = (const float*)d_in[23];
    const int*   ui0_r = (const int*)d_in[24]; const int* ui0_c = (const int*)d_in[25];
    const float* ui0_v = (const float*)d_in[26];
    const int*   iu0_r = (const int*)d_in[27]; const int* iu0_c = (const int*)d_in[28];
    const float* iu0_v = (const float*)d_in[29];
    const float* d_i_1 = (const float*)d_in[30];
    const float* d_j_1 = (const float*)d_in[31];
    const float* d_i_0 = (const float*)d_in[32];
    const float* d_j_0 = (const float*)d_in[33];
    float* out = (float*)d_out;

    // workspace layout
    char* p = (char*)d_ws;
    size_t off = 0;
    auto alloc = [&](size_t bytes) { char* q = p + off; off += align256(bytes); return q; };
    float* stat  = (float*)alloc(size_t(SN) * KN * 4);
    float* kdiff = (float*)alloc(size_t(EN) * KN * 4);
    float* sW1   = (float*)alloc(size_t(SN) * KN * 4);
    float* sW0   = (float*)alloc(size_t(SN) * KN * 4);
    float* kW1   = (float*)alloc(size_t(EN) * KN * 4);
    float* kW0   = (float*)alloc(size_t(EN) * KN * 4);
    int*   rp_ui1 = (int*)alloc((SN + 1) * 4);
    int*   cs_ui1 = (int*)alloc(size_t(NE) * 4);
    float* vs_ui1 = (float*)alloc(size_t(NE) * 4);
    int*   rp_ui0 = (int*)alloc((SN + 1) * 4);
    int*   cs_ui0 = (int*)alloc(size_t(NE) * 4);
    float* vs_ui0 = (float*)alloc(size_t(NE) * 4);
    int*   rp_iu1 = (int*)alloc((EN + 1) * 4);
    int*   cs_iu1 = (int*)alloc(size_t(NE) * 4);
    float* vs_iu1 = (float*)alloc(size_t(NE) * 4);
    int*   rp_iu0 = (int*)alloc((EN + 1) * 4);
    int*   cs_iu0 = (int*)alloc(size_t(NE) * 4);
    float* vs_iu0 = (float*)alloc(size_t(NE) * 4);
    int*   cursor = (int*)alloc((SN + 1) * 4);
    float* xh  = (float*)alloc(size_t(BN) * KN * 4);
    float* h1  = (float*)alloc(size_t(BN) * 256 * 4);
    float* h2  = (float*)alloc(size_t(BN) * 128 * 4);
    if (off > ws_size) return;  // workspace too small; fail visibly

    const int EG = (NE + 255) / 256;

    // ---- build 4 CSRs ----
    auto build_csr = [&](const int* rows, const int* cols, const float* vals,
                         int nrows, int* rp, int* cs, float* vs) {
        hipMemsetAsync(cursor, 0, size_t(nrows) * 4, stream);
        count_kernel<<<EG, 256, 0, stream>>>(rows, cursor, NE);
        exscan_kernel<<<1, 1024, 0, stream>>>(cursor, rp, nrows);
        hipMemcpyAsync(cursor, rp, size_t(nrows) * 4, hipMemcpyDeviceToDevice, stream);
        fill_kernel<<<EG, 256, 0, stream>>>(rows, cols, vals, cursor, cs, vs, NE);
    };
    build_csr(ui1_r, ui1_c, ui1_v, SN, rp_ui1, cs_ui1, vs_ui1);
    build_csr(ui0_r, ui0_c, ui0_v, SN, rp_ui0, cs_ui0, vs_ui0);
    build_csr(iu1_r, iu1_c, iu1_v, EN, rp_iu1, cs_iu1, vs_iu1);
    build_csr(iu0_r, iu0_c, iu0_v, EN, rp_iu0, cs_iu0, vs_iu0);

    // ---- projections: stat = stu_emb @ kn_base^T, kdiff = exer_emb @ kn_base^T ----
    gemm_xwT<DN, KN, 32, false, false><<<(SN + 31) / 32, 256, 0, stream>>>(
        stu_emb, kn_base, nullptr, stat, SN);
    gemm_xwT<DN, KN, 32, false, false><<<(EN + 31) / 32, 256, 0, stream>>>(
        exer_emb, kn_base, nullptr, kdiff, EN);

    // ---- GCN layers ----
    for (int l = 0; l < NLAYER; ++l) {
        gemm_xwT<KN, KN, 32, false, false><<<(SN + 31) / 32, 256, 0, stream>>>(
            stat, W1_w, nullptr, sW1, SN);
        gemm_xwT<KN, KN, 32, false, false><<<(SN + 31) / 32, 256, 0, stream>>>(
            stat, W0_w, nullptr, sW0, SN);
        gemm_xwT<KN, KN, 32, false, false><<<(EN + 31) / 32, 256, 0, stream>>>(
            kdiff, W1_w, nullptr, kW1, EN);
        gemm_xwT<KN, KN, 32, false, false><<<(EN + 31) / 32, 256, 0, stream>>>(
            kdiff, W0_w, nullptr, kW0, EN);
        // stat_new = A1(x)kW1 + A0(x)kW0 + d_i1.*sW1 + d_i0.*sW0 + (b1+b0)
        spmm_fused<<<(SN + 3) / 4, 256, 0, stream>>>(
            rp_ui1, cs_ui1, vs_ui1, kW1, rp_ui0, cs_ui0, vs_ui0, kW0,
            d_i_1, d_i_0, sW1, sW0, W1_b, W0_b, stat, SN);
        // kdiff_new = B1(x)sW1 + B0(x)sW0 + d_j1.*kW1 + d_j0.*kW0 + (b1+b0)
        spmm_fused<<<(EN + 3) / 4, 256, 0, stream>>>(
            rp_iu1, cs_iu1, vs_iu1, sW1, rp_iu0, cs_iu0, vs_iu0, sW0,
            d_j_1, d_j_0, kW1, kW0, W1_b, W0_b, kdiff, EN);
    }

    // ---- head ----
    head1_kernel<<<BN, 128, 0, stream>>>(stu_id, exer_id, kn_emb, stat, kdiff,
                                         stu_bias, e_disc, xh);
    gemm_xwT<128, 256, 16, true, true><<<BN / 16, 256, 0, stream>>>(xh, pn1_w, pn1_b, h1, BN);
    gemm_xwT<256, 128, 32, true, true><<<BN / 32, 256, 0, stream>>>(h1, pn2_w, pn2_b, h2, BN);
    pn3_kernel<<<BN / 256, 256, 0, stream>>>(h2, pn3_w, pn3_b, out);
    (void)out_size; (void)n_in; (void)in_sizes;
}

// Round 2
// 1329.295 us; speedup vs baseline: 1.9300x; 1.9300x over previous
//
#include <hip/hip_runtime.h>
#include <hip/hip_bf16.h>

// Problem constants (from reference)
#define SN 50000
#define EN 20000
#define KN 128
#define DN 64
#define BN 4096
#define NE 1000000
#define NLAYER 3
#define EGRID ((NE + 255) / 256)

typedef float f32x4 __attribute__((ext_vector_type(4)));
typedef short bf16x8 __attribute__((ext_vector_type(8)));

__device__ __forceinline__ float sigmoidf_(float v) { return 1.f / (1.f + __expf(-v)); }
__device__ __forceinline__ float bf_lo(unsigned u) { return __uint_as_float(u << 16); }
__device__ __forceinline__ float bf_hi(unsigned u) { return __uint_as_float(u & 0xffff0000u); }
__device__ __forceinline__ float bf_one(unsigned short s) { return __uint_as_float((unsigned)s << 16); }
__device__ __forceinline__ unsigned packbf2(float a, float b) {
    __hip_bfloat16 ha = __float2bfloat16(a), hb = __float2bfloat16(b);
    unsigned short ua = *(unsigned short*)&ha, ub = *(unsigned short*)&hb;
    return (unsigned)ua | ((unsigned)ub << 16);
}
__device__ __forceinline__ unsigned short packbf1(float a) {
    __hip_bfloat16 ha = __float2bfloat16(a);
    return *(unsigned short*)&ha;
}

// ---------------------------------------------------------------------------
// CSR build (all 4 adjacencies in one kernel each)
// ---------------------------------------------------------------------------
struct Csr4 {
    const int* rows[4]; const int* cols[4]; const float* vals[4];
    int* cnt[4]; int* rp[4]; int* cur[4]; int* cs[4]; float* vs[4];
    int n[4];
};

__global__ __launch_bounds__(256) void count_all(Csr4 c) {
    int a = blockIdx.x / EGRID;
    int i = (blockIdx.x - a * EGRID) * 256 + threadIdx.x;
    if (i < NE) atomicAdd(&c.cnt[a][c.rows[a][i]], 1);
}

__global__ __launch_bounds__(1024) void exscan_all(Csr4 c) {
    __shared__ int part[1024];
    const int a = blockIdx.x;
    const int n = c.n[a];
    const int* cnt = c.cnt[a];
    int* rp = c.rp[a];
    int* cur = c.cur[a];
    const int t = threadIdx.x;
    const int chunk = (n + 1023) / 1024;
    const int beg = t * chunk;
    const int end = min(beg + chunk, n);
    int s = 0;
    for (int i = beg; i < end; ++i) s += cnt[i];
    part[t] = s;
    __syncthreads();
    for (int off = 1; off < 1024; off <<= 1) {
        int v = part[t];
        int u = (t >= off) ? part[t - off] : 0;
        __syncthreads();
        part[t] = v + u;
        __syncthreads();
    }
    int prefix = (t == 0) ? 0 : part[t - 1];
    for (int i = beg; i < end; ++i) { rp[i] = prefix; cur[i] = prefix; prefix += cnt[i]; }
    if (t == 1023) rp[n] = part[1023];
}

__global__ __launch_bounds__(256) void fill_all(Csr4 c) {
    int a = blockIdx.x / EGRID;
    int i = (blockIdx.x - a * EGRID) * 256 + threadIdx.x;
    if (i < NE) {
        int r = c.rows[a][i];
        int p = atomicAdd(&c.cur[a][r], 1);
        c.cs[a][p] = c.cols[a][i];
        c.vs[a][p] = c.vals[a][i];
    }
}

// ---------------------------------------------------------------------------
// fp32 -> bf16 conversion (n must be even)
// ---------------------------------------------------------------------------
__global__ __launch_bounds__(256) void f2bf(const float* __restrict__ src,
                                            unsigned short* __restrict__ dst, int n2) {
    int i = blockIdx.x * 256 + threadIdx.x;
    if (i < n2) {
        float2 f = ((const float2*)src)[i];
        ((unsigned*)dst)[i] = packbf2(f.x, f.y);
    }
}

// ---------------------------------------------------------------------------
// MFMA GEMM: out[M,128](bf16) = X[M,KK](bf16) @ W[128,KK]^T(bf16)
// block = 256 threads = 4 waves; 64 rows/block (16/wave); W staged in LDS.
// A-frag: lane holds A[m=lane&15][k=quad*8+j]; B-frag: B^T row n=lane&15.
// D: col=lane&15, row=quad*4+reg.
// ---------------------------------------------------------------------------
template <int KK>
__global__ __launch_bounds__(256) void gemm_mfma(const unsigned short* __restrict__ X,
                                                 const unsigned short* __restrict__ W,
                                                 unsigned short* __restrict__ out, int M) {
    constexpr int PITCH = KK + 8;  // +16B: row stride 4.25 bank-rows -> only 2-way (free)
    __shared__ unsigned short Wl[128 * PITCH];
    const int t = threadIdx.x;
    for (int idx = t * 8; idx < 128 * KK; idx += 2048) {
        int r = idx / KK, k = idx - r * KK;
        *(uint4*)(&Wl[r * PITCH + k]) = *(const uint4*)(&W[idx]);
    }
    __syncthreads();
    const int lane = t & 63;
    const int nm = lane & 15;          // m for A, n-within-tile for B, col for D
    const int quad = lane >> 4;
    const int row0 = blockIdx.x * 64 + (t >> 6) * 16;
    if (row0 >= M) return;             // M % 16 == 0 for all callers

    f32x4 acc[8];
#pragma unroll
    for (int nt = 0; nt < 8; ++nt) acc[nt] = (f32x4){0.f, 0.f, 0.f, 0.f};

    const unsigned short* xrow = X + (size_t)(row0 + nm) * KK + quad * 8;
#pragma unroll
    for (int ks = 0; ks < KK / 32; ++ks) {
        bf16x8 a = *(const bf16x8*)(xrow + ks * 32);
#pragma unroll
        for (int nt = 0; nt < 8; ++nt) {
            bf16x8 b = *(const bf16x8*)(&Wl[(nt * 16 + nm) * PITCH + ks * 32 + quad * 8]);
            acc[nt] = __builtin_amdgcn_mfma_f32_16x16x32_bf16(a, b, acc[nt], 0, 0, 0);
        }
    }
    unsigned short* orow = out + (size_t)(row0 + quad * 4) * 128 + nm;
#pragma unroll
    for (int r = 0; r < 4; ++r)
#pragma unroll
        for (int nt = 0; nt < 8; ++nt)
            orow[(size_t)r * 128 + nt * 16] = packbf1(acc[nt][r]);
}

// ---------------------------------------------------------------------------
// Fused SPMM (bf16 tables): out = A1(x)g1 + A0(x)g0 + dA.*yA + dB.*yB + (b1+b0)
// wave per row; lane l owns columns 2l, 2l+1 (one uint = 2 bf16 per access).
// ---------------------------------------------------------------------------
__global__ __launch_bounds__(256) void spmm_fused(
    const int* __restrict__ rp1, const int* __restrict__ c1, const float* __restrict__ v1,
    const unsigned short* __restrict__ g1,
    const int* __restrict__ rp0, const int* __restrict__ c0, const float* __restrict__ v0,
    const unsigned short* __restrict__ g0,
    const float* __restrict__ dA, const float* __restrict__ dB,
    const unsigned short* __restrict__ yA, const unsigned short* __restrict__ yB,
    const float* __restrict__ b1, const float* __restrict__ b0,
    unsigned short* __restrict__ out, int nrows) {
    const int wave = (blockIdx.x * 256 + threadIdx.x) >> 6;
    const int lane = threadIdx.x & 63;
    if (wave >= nrows) return;
    const int r = wave;
    const int col2 = lane * 2;
    float acc0 = 0.f, acc1 = 0.f;

    {
        int e = rp1[r], eend = rp1[r + 1];
        for (; e + 4 <= eend; e += 4) {
            int ca = c1[e], cb = c1[e + 1], cc = c1[e + 2], cd = c1[e + 3];
            float va = v1[e], vb = v1[e + 1], vc = v1[e + 2], vd = v1[e + 3];
            unsigned ua = *(const unsigned*)&g1[(ca << 7) + col2];
            unsigned ub = *(const unsigned*)&g1[(cb << 7) + col2];
            unsigned uc = *(const unsigned*)&g1[(cc << 7) + col2];
            unsigned ud = *(const unsigned*)&g1[(cd << 7) + col2];
            acc0 += va * bf_lo(ua) + vb * bf_lo(ub) + vc * bf_lo(uc) + vd * bf_lo(ud);
            acc1 += va * bf_hi(ua) + vb * bf_hi(ub) + vc * bf_hi(uc) + vd * bf_hi(ud);
        }
        for (; e < eend; ++e) {
            int ca = c1[e]; float va = v1[e];
            unsigned ua = *(const unsigned*)&g1[(ca << 7) + col2];
            acc0 += va * bf_lo(ua);
            acc1 += va * bf_hi(ua);
        }
    }
    {
        int e = rp0[r], eend = rp0[r + 1];
        for (; e + 4 <= eend; e += 4) {
            int ca = c0[e], cb = c0[e + 1], cc = c0[e + 2], cd = c0[e + 3];
            float va = v0[e], vb = v0[e + 1], vc = v0[e + 2], vd = v0[e + 3];
            unsigned ua = *(const unsigned*)&g0[(ca << 7) + col2];
            unsigned ub = *(const unsigned*)&g0[(cb << 7) + col2];
            unsigned uc = *(const unsigned*)&g0[(cc << 7) + col2];
            unsigned ud = *(const unsigned*)&g0[(cd << 7) + col2];
            acc0 += va * bf_lo(ua) + vb * bf_lo(ub) + vc * bf_lo(uc) + vd * bf_lo(ud);
            acc1 += va * bf_hi(ua) + vb * bf_hi(ub) + vc * bf_hi(uc) + vd * bf_hi(ud);
        }
        for (; e < eend; ++e) {
            int ca = c0[e]; float va = v0[e];
            unsigned ua = *(const unsigned*)&g0[(ca << 7) + col2];
            acc0 += va * bf_lo(ua);
            acc1 += va * bf_hi(ua);
        }
    }
    const float da = dA[r], db = dB[r];
    const int base = r << 7;
    unsigned uya = *(const unsigned*)&yA[base + col2];
    unsigned uyb = *(const unsigned*)&yB[base + col2];
    acc0 += da * bf_lo(uya) + db * bf_lo(uyb) + b1[col2] + b0[col2];
    acc1 += da * bf_hi(uya) + db * bf_hi(uyb) + b1[col2 + 1] + b0[col2 + 1];
    *(unsigned*)&out[base + col2] = packbf2(acc0, acc1);
}

// ---------------------------------------------------------------------------
// fp32 tiled GEMM for the head: out = act( X @ |W|^T + b )
// ---------------------------------------------------------------------------
template <int KK, int NCOLS, int ROWS, bool ABSW, bool SIG>
__global__ __launch_bounds__(256) void gemm_xwT(const float* __restrict__ X,
                                                const float* __restrict__ W,
                                                const float* __restrict__ bias,
                                                float* __restrict__ out, int M) {
    constexpr int KP = 32;
    constexpr int NG = 256 / NCOLS;
    constexpr int RT = ROWS / NG;
    __shared__ float BT[KP * (NCOLS + 1)];
    __shared__ float Xl[ROWS * (KK + 1)];
    const int t = threadIdx.x;
    const int j = t % NCOLS;
    const int rg = t / NCOLS;
    const int row0 = blockIdx.x * ROWS;

    for (int idx = t; idx < ROWS * KK; idx += 256) {
        int r = idx / KK, k = idx % KK;
        int gr = row0 + r;
        Xl[r * (KK + 1) + k] = (gr < M) ? X[gr * KK + k] : 0.f;
    }
    float acc[RT];
#pragma unroll
    for (int i = 0; i < RT; ++i) acc[i] = 0.f;

    for (int k0 = 0; k0 < KK; k0 += KP) {
        __syncthreads();
        for (int idx = t; idx < NCOLS * KP; idx += 256) {
            int jj = idx / KP, kp = idx % KP;
            float w = W[jj * KK + k0 + kp];
            BT[kp * (NCOLS + 1) + jj] = ABSW ? fabsf(w) : w;
        }
        __syncthreads();
#pragma unroll
        for (int kp = 0; kp < KP; ++kp) {
            float b = BT[kp * (NCOLS + 1) + j];
#pragma unroll
            for (int rr = 0; rr < RT; ++rr)
                acc[rr] += Xl[(rg * RT + rr) * (KK + 1) + k0 + kp] * b;
        }
    }
    float bj = bias ? bias[j] : 0.f;
#pragma unroll
    for (int rr = 0; rr < RT; ++rr) {
        int gr = row0 + rg * RT + rr;
        if (gr < M) {
            float v = acc[rr] + bj;
            out[gr * NCOLS + j] = SIG ? sigmoidf_(v) : v;
        }
    }
}

// ---------------------------------------------------------------------------
// Head kernels
// ---------------------------------------------------------------------------
__global__ __launch_bounds__(128) void head1_kernel(
    const int* __restrict__ stu_id, const int* __restrict__ exer_id,
    const float* __restrict__ kn_emb, const unsigned short* __restrict__ stat,
    const unsigned short* __restrict__ kdiff, const float* __restrict__ stu_bias,
    const float* __restrict__ e_disc, float* __restrict__ x) {
    const int b = blockIdx.x;
    const int k = threadIdx.x;
    const int sid = stu_id[b], eid = exer_id[b];
    float disc = sigmoidf_(e_disc[eid]);
    float sb = sigmoidf_(bf_one(stat[(sid << 7) + k]) + stu_bias[sid]);
    float kd = sigmoidf_(bf_one(kdiff[(eid << 7) + k]));
    x[(b << 7) + k] = disc * (sb - kd) * kn_emb[(b << 7) + k];
}

__global__ __launch_bounds__(256) void pn3_kernel(const float* __restrict__ h2,
                                                  const float* __restrict__ w3,
                                                  const float* __restrict__ b3,
                                                  float* __restrict__ out) {
    __shared__ float wl[128];
    const int t = threadIdx.x;
    if (t < 128) wl[t] = fabsf(w3[t]);
    __syncthreads();
    const int b = blockIdx.x * 256 + t;
    float acc = 0.f;
#pragma unroll 4
    for (int k = 0; k < 128; ++k) acc += h2[(b << 7) + k] * wl[k];
    out[b] = sigmoidf_(acc + b3[0]);
}

// ---------------------------------------------------------------------------
// Launch
// ---------------------------------------------------------------------------
static inline size_t align256(size_t x) { return (x + 255) & ~size_t(255); }

extern "C" void kernel_launch(void* const* d_in, const int* in_sizes, int n_in,
                              void* d_out, int out_size, void* d_ws, size_t ws_size,
                              hipStream_t stream) {
    const int*   stu_id   = (const int*)d_in[0];
    const int*   exer_id  = (const int*)d_in[1];
    const float* kn_emb   = (const float*)d_in[2];
    const float* stu_emb  = (const float*)d_in[3];
    const float* exer_emb = (const float*)d_in[4];
    const float* kn_base  = (const float*)d_in[5];
    const float* stu_bias = (const float*)d_in[6];
    const float* e_disc   = (const float*)d_in[7];
    const float* W1_w     = (const float*)d_in[8];
    const float* W1_b     = (const float*)d_in[9];
    const float* W0_w     = (const float*)d_in[10];
    const float* W0_b     = (const float*)d_in[11];
    const float* pn1_w    = (const float*)d_in[12];
    const float* pn1_b    = (const float*)d_in[13];
    const float* pn2_w    = (const float*)d_in[14];
    const float* pn2_b    = (const float*)d_in[15];
    const float* pn3_w    = (const float*)d_in[16];
    const float* pn3_b    = (const float*)d_in[17];
    const int*   ui1_r = (const int*)d_in[18]; const int* ui1_c = (const int*)d_in[19];
    const float* ui1_v = (const float*)d_in[20];
    const int*   iu1_r = (const int*)d_in[21]; const int* iu1_c = (const int*)d_in[22];
    const float* iu1_v = (const float*)d_in[23];
    const int*   ui0_r = (const int*)d_in[24]; const int* ui0_c = (const int*)d_in[25];
    const float* ui0_v = (const float*)d_in[26];
    const int*   iu0_r = (const int*)d_in[27]; const int* iu0_c = (const int*)d_in[28];
    const float* iu0_v = (const float*)d_in[29];
    const float* d_i_1 = (const float*)d_in[30];
    const float* d_j_1 = (const float*)d_in[31];
    const float* d_i_0 = (const float*)d_in[32];
    const float* d_j_0 = (const float*)d_in[33];
    float* out = (float*)d_out;

    typedef unsigned short u16;
    char* p = (char*)d_ws;
    size_t off = 0;
    auto alloc = [&](size_t bytes) { char* q = p + off; off += align256(bytes); return q; };
    // bf16 state + projected tables
    u16* stat  = (u16*)alloc(size_t(SN) * KN * 2);
    u16* kdiff = (u16*)alloc(size_t(EN) * KN * 2);
    u16* sW1   = (u16*)alloc(size_t(SN) * KN * 2);
    u16* sW0   = (u16*)alloc(size_t(SN) * KN * 2);
    u16* kW1   = (u16*)alloc(size_t(EN) * KN * 2);
    u16* kW0   = (u16*)alloc(size_t(EN) * KN * 2);
    // bf16 copies of inputs
    u16* Xs  = (u16*)alloc(size_t(SN) * DN * 2);
    u16* Xe  = (u16*)alloc(size_t(EN) * DN * 2);
    u16* Kb  = (u16*)alloc(size_t(KN) * DN * 2);
    u16* Wb1 = (u16*)alloc(size_t(KN) * KN * 2);
    u16* Wb0 = (u16*)alloc(size_t(KN) * KN * 2);
    // CSR
    int*   cnt_all = (int*)alloc(size_t(2 * SN + 2 * EN) * 4);
    int*   cur_all = (int*)alloc(size_t(2 * SN + 2 * EN) * 4);
    int*   rp_ui1 = (int*)alloc((SN + 1) * 4);
    int*   rp_ui0 = (int*)alloc((SN + 1) * 4);
    int*   rp_iu1 = (int*)alloc((EN + 1) * 4);
    int*   rp_iu0 = (int*)alloc((EN + 1) * 4);
    int*   cs_ui1 = (int*)alloc(size_t(NE) * 4);
    float* vs_ui1 = (float*)alloc(size_t(NE) * 4);
    int*   cs_ui0 = (int*)alloc(size_t(NE) * 4);
    float* vs_ui0 = (float*)alloc(size_t(NE) * 4);
    int*   cs_iu1 = (int*)alloc(size_t(NE) * 4);
    float* vs_iu1 = (float*)alloc(size_t(NE) * 4);
    int*   cs_iu0 = (int*)alloc(size_t(NE) * 4);
    float* vs_iu0 = (float*)alloc(size_t(NE) * 4);
    // head
    float* xh = (float*)alloc(size_t(BN) * KN * 4);
    float* h1 = (float*)alloc(size_t(BN) * 256 * 4);
    float* h2 = (float*)alloc(size_t(BN) * 128 * 4);
    if (off > ws_size) return;

    // ---- CSR build: 1 memset + 3 fused kernels ----
    Csr4 c;
    c.rows[0] = ui1_r; c.cols[0] = ui1_c; c.vals[0] = ui1_v;
    c.rows[1] = ui0_r; c.cols[1] = ui0_c; c.vals[1] = ui0_v;
    c.rows[2] = iu1_r; c.cols[2] = iu1_c; c.vals[2] = iu1_v;
    c.rows[3] = iu0_r; c.cols[3] = iu0_c; c.vals[3] = iu0_v;
    c.cnt[0] = cnt_all;          c.cur[0] = cur_all;
    c.cnt[1] = cnt_all + SN;     c.cur[1] = cur_all + SN;
    c.cnt[2] = cnt_all + 2 * SN; c.cur[2] = cur_all + 2 * SN;
    c.cnt[3] = cnt_all + 2 * SN + EN; c.cur[3] = cur_all + 2 * SN + EN;
    c.rp[0] = rp_ui1; c.rp[1] = rp_ui0; c.rp[2] = rp_iu1; c.rp[3] = rp_iu0;
    c.cs[0] = cs_ui1; c.vs[0] = vs_ui1;
    c.cs[1] = cs_ui0; c.vs[1] = vs_ui0;
    c.cs[2] = cs_iu1; c.vs[2] = vs_iu1;
    c.cs[3] = cs_iu0; c.vs[3] = vs_iu0;
    c.n[0] = SN; c.n[1] = SN; c.n[2] = EN; c.n[3] = EN;

    hipMemsetAsync(cnt_all, 0, size_t(2 * SN + 2 * EN) * 4, stream);
    count_all<<<4 * EGRID, 256, 0, stream>>>(c);
    exscan_all<<<4, 1024, 0, stream>>>(c);
    fill_all<<<4 * EGRID, 256, 0, stream>>>(c);

    // ---- fp32 -> bf16 conversions ----
    f2bf<<<(SN * DN / 2 + 255) / 256, 256, 0, stream>>>(stu_emb, Xs, SN * DN / 2);
    f2bf<<<(EN * DN / 2 + 255) / 256, 256, 0, stream>>>(exer_emb, Xe, EN * DN / 2);
    f2bf<<<(KN * DN / 2 + 255) / 256, 256, 0, stream>>>(kn_base, Kb, KN * DN / 2);
    f2bf<<<(KN * KN / 2 + 255) / 256, 256, 0, stream>>>(W1_w, Wb1, KN * KN / 2);
    f2bf<<<(KN * KN / 2 + 255) / 256, 256, 0, stream>>>(W0_w, Wb0, KN * KN / 2);

    // ---- projections ----
    gemm_mfma<DN><<<(SN + 63) / 64, 256, 0, stream>>>(Xs, Kb, stat, SN);
    gemm_mfma<DN><<<(EN + 63) / 64, 256, 0, stream>>>(Xe, Kb, kdiff, EN);

    // ---- GCN layers ----
    for (int l = 0; l < NLAYER; ++l) {
        gemm_mfma<KN><<<(SN + 63) / 64, 256, 0, stream>>>(stat, Wb1, sW1, SN);
        gemm_mfma<KN><<<(SN + 63) / 64, 256, 0, stream>>>(stat, Wb0, sW0, SN);
        gemm_mfma<KN><<<(EN + 63) / 64, 256, 0, stream>>>(kdiff, Wb1, kW1, EN);
        gemm_mfma<KN><<<(EN + 63) / 64, 256, 0, stream>>>(kdiff, Wb0, kW0, EN);
        spmm_fused<<<(SN + 3) / 4, 256, 0, stream>>>(
            rp_ui1, cs_ui1, vs_ui1, kW1, rp_ui0, cs_ui0, vs_ui0, kW0,
            d_i_1, d_i_0, sW1, sW0, W1_b, W0_b, stat, SN);
        spmm_fused<<<(EN + 3) / 4, 256, 0, stream>>>(
            rp_iu1, cs_iu1, vs_iu1, sW1, rp_iu0, cs_iu0, vs_iu0, sW0,
            d_j_1, d_j_0, kW1, kW0, W1_b, W0_b, kdiff, EN);
    }

    // ---- head ----
    head1_kernel<<<BN, 128, 0, stream>>>(stu_id, exer_id, kn_emb, stat, kdiff,
                                         stu_bias, e_disc, xh);
    gemm_xwT<128, 256, 16, true, true><<<BN / 16, 256, 0, stream>>>(xh, pn1_w, pn1_b, h1, BN);
    gemm_xwT<256, 128, 32, true, true><<<BN / 32, 256, 0, stream>>>(h1, pn2_w, pn2_b, h2, BN);
    pn3_kernel<<<BN / 256, 256, 0, stream>>>(h2, pn3_w, pn3_b, out);
    (void)out_size; (void)n_in; (void)in_sizes;
}

// Round 3
// 1322.521 us; speedup vs baseline: 1.9399x; 1.0051x over previous
//
#include <hip/hip_runtime.h>
#include <hip/hip_bf16.h>

// Problem constants (from reference)
#define SN 50000
#define EN 20000
#define KN 128
#define DN 64
#define BN 4096
#define NE 1000000
#define NLAYER 3
#define EGRID ((NE + 255) / 256)

typedef float f32x4 __attribute__((ext_vector_type(4)));
typedef short bf16x8 __attribute__((ext_vector_type(8)));

__device__ __forceinline__ float sigmoidf_(float v) { return 1.f / (1.f + __expf(-v)); }
__device__ __forceinline__ float bf_lo(unsigned u) { return __uint_as_float(u << 16); }
__device__ __forceinline__ float bf_hi(unsigned u) { return __uint_as_float(u & 0xffff0000u); }
__device__ __forceinline__ float bf_one(unsigned short s) { return __uint_as_float((unsigned)s << 16); }
__device__ __forceinline__ unsigned packbf2(float a, float b) {
    __hip_bfloat16 ha = __float2bfloat16(a), hb = __float2bfloat16(b);
    unsigned short ua = *(unsigned short*)&ha, ub = *(unsigned short*)&hb;
    return (unsigned)ua | ((unsigned)ub << 16);
}
__device__ __forceinline__ unsigned short packbf1(float a) {
    __hip_bfloat16 ha = __float2bfloat16(a);
    return *(unsigned short*)&ha;
}

// ---------------------------------------------------------------------------
// CSR build (all 4 adjacencies; edge record = int2{col, val_bits} 8B combined)
// ---------------------------------------------------------------------------
struct Csr4 {
    const int* rows[4]; const int* cols[4]; const float* vals[4];
    int* cnt[4]; int* rp[4]; int* cur[4]; int2* cv[4];
    int n[4];
};

__global__ __launch_bounds__(256) void count_all(Csr4 c) {
    int a = blockIdx.x / EGRID;
    int i = (blockIdx.x - a * EGRID) * 256 + threadIdx.x;
    if (i < NE) atomicAdd(&c.cnt[a][c.rows[a][i]], 1);
}

__global__ __launch_bounds__(1024) void exscan_all(Csr4 c) {
    __shared__ int part[1024];
    const int a = blockIdx.x;
    const int n = c.n[a];
    const int* cnt = c.cnt[a];
    int* rp = c.rp[a];
    int* cur = c.cur[a];
    const int t = threadIdx.x;
    const int chunk = (n + 1023) / 1024;
    const int beg = t * chunk;
    const int end = min(beg + chunk, n);
    int s = 0;
    for (int i = beg; i < end; ++i) s += cnt[i];
    part[t] = s;
    __syncthreads();
    for (int off = 1; off < 1024; off <<= 1) {
        int v = part[t];
        int u = (t >= off) ? part[t - off] : 0;
        __syncthreads();
        part[t] = v + u;
        __syncthreads();
    }
    int prefix = (t == 0) ? 0 : part[t - 1];
    for (int i = beg; i < end; ++i) { rp[i] = prefix; cur[i] = prefix; prefix += cnt[i]; }
    if (t == 1023) rp[n] = part[1023];
}

__global__ __launch_bounds__(256) void fill_all(Csr4 c) {
    int a = blockIdx.x / EGRID;
    int i = (blockIdx.x - a * EGRID) * 256 + threadIdx.x;
    if (i < NE) {
        int r = c.rows[a][i];
        int p = atomicAdd(&c.cur[a][r], 1);
        c.cv[a][p] = make_int2(c.cols[a][i], __float_as_int(c.vals[a][i]));
    }
}

// ---------------------------------------------------------------------------
// fp32 -> bf16 conversion (n2 = n/2)
// ---------------------------------------------------------------------------
__global__ __launch_bounds__(256) void f2bf(const float* __restrict__ src,
                                            unsigned short* __restrict__ dst, int n2) {
    int i = blockIdx.x * 256 + threadIdx.x;
    if (i < n2) {
        float2 f = ((const float2*)src)[i];
        ((unsigned*)dst)[i] = packbf2(f.x, f.y);
    }
}

// ---------------------------------------------------------------------------
// MFMA GEMM (projections): out[M,128](bf16) = X[M,KK](bf16) @ W[128,KK]^T(bf16)
// ---------------------------------------------------------------------------
template <int KK>
__global__ __launch_bounds__(256) void gemm_mfma(const unsigned short* __restrict__ X,
                                                 const unsigned short* __restrict__ W,
                                                 unsigned short* __restrict__ out, int M) {
    constexpr int PITCH = KK + 8;
    __shared__ unsigned short Wl[128 * PITCH];
    const int t = threadIdx.x;
    for (int idx = t * 8; idx < 128 * KK; idx += 2048) {
        int r = idx / KK, k = idx - r * KK;
        *(uint4*)(&Wl[r * PITCH + k]) = *(const uint4*)(&W[idx]);
    }
    __syncthreads();
    const int lane = t & 63;
    const int nm = lane & 15;
    const int quad = lane >> 4;
    const int row0 = blockIdx.x * 64 + (t >> 6) * 16;
    if (row0 >= M) return;

    f32x4 acc[8];
#pragma unroll
    for (int nt = 0; nt < 8; ++nt) acc[nt] = (f32x4){0.f, 0.f, 0.f, 0.f};

    const unsigned short* xrow = X + (size_t)(row0 + nm) * KK + quad * 8;
#pragma unroll
    for (int ks = 0; ks < KK / 32; ++ks) {
        bf16x8 a = *(const bf16x8*)(xrow + ks * 32);
#pragma unroll
        for (int nt = 0; nt < 8; ++nt) {
            bf16x8 b = *(const bf16x8*)(&Wl[(nt * 16 + nm) * PITCH + ks * 32 + quad * 8]);
            acc[nt] = __builtin_amdgcn_mfma_f32_16x16x32_bf16(a, b, acc[nt], 0, 0, 0);
        }
    }
    unsigned short* orow = out + (size_t)(row0 + quad * 4) * 128 + nm;
#pragma unroll
    for (int r = 0; r < 4; ++r)
#pragma unroll
        for (int nt = 0; nt < 8; ++nt)
            orow[(size_t)r * 128 + nt * 16] = packbf1(acc[nt][r]);
}

// ---------------------------------------------------------------------------
// Fused dual-weight MFMA GEMM (one GCN layer side, in-place safe):
//   out = (agg1 + d1.*y)@W1^T + (agg0 + d0.*y)@W0^T + (b1+b0)
// Both weights staged in LDS (69.6 KB). Each wave: 16 rows x 128 cols.
// ---------------------------------------------------------------------------
__global__ __launch_bounds__(256) void gemm2_mfma(
    const unsigned short* __restrict__ agg1, const unsigned short* __restrict__ agg0,
    const unsigned short* __restrict__ y,
    const float* __restrict__ d1, const float* __restrict__ d0,
    const unsigned short* __restrict__ W1, const unsigned short* __restrict__ W0,
    const float* __restrict__ b1, const float* __restrict__ b0,
    unsigned short* __restrict__ out, int M) {
    constexpr int PITCH = 136;
    __shared__ unsigned short Wl[2 * 128 * PITCH];
    const int t = threadIdx.x;
    for (int idx = t * 8; idx < 128 * 128; idx += 2048) {
        int r = idx >> 7, k = idx & 127;
        *(uint4*)(&Wl[r * PITCH + k]) = *(const uint4*)(&W1[idx]);
        *(uint4*)(&Wl[128 * PITCH + r * PITCH + k]) = *(const uint4*)(&W0[idx]);
    }
    __syncthreads();
    const int lane = t & 63;
    const int nm = lane & 15;
    const int quad = lane >> 4;
    const int row0 = blockIdx.x * 64 + (t >> 6) * 16;
    if (row0 >= M) return;

    const float d1v = d1[row0 + nm];
    const float d0v = d0[row0 + nm];

    f32x4 acc[8];
#pragma unroll
    for (int nt = 0; nt < 8; ++nt) acc[nt] = (f32x4){0.f, 0.f, 0.f, 0.f};

    const size_t rbase = (size_t)(row0 + nm) * 128 + quad * 8;
#pragma unroll
    for (int ks = 0; ks < 4; ++ks) {
        uint4 ua1 = *(const uint4*)(agg1 + rbase + ks * 32);
        uint4 ua0 = *(const uint4*)(agg0 + rbase + ks * 32);
        uint4 uy  = *(const uint4*)(y    + rbase + ks * 32);
        uint4 p1, p0;
        {
            unsigned* a1 = (unsigned*)&ua1; unsigned* a0 = (unsigned*)&ua0;
            unsigned* yy = (unsigned*)&uy;
            unsigned* q1 = (unsigned*)&p1; unsigned* q0 = (unsigned*)&p0;
#pragma unroll
            for (int w = 0; w < 4; ++w) {
                float ylo = bf_lo(yy[w]), yhi = bf_hi(yy[w]);
                q1[w] = packbf2(bf_lo(a1[w]) + d1v * ylo, bf_hi(a1[w]) + d1v * yhi);
                q0[w] = packbf2(bf_lo(a0[w]) + d0v * ylo, bf_hi(a0[w]) + d0v * yhi);
            }
        }
        bf16x8 af1 = *(bf16x8*)&p1;
        bf16x8 af0 = *(bf16x8*)&p0;
#pragma unroll
        for (int nt = 0; nt < 8; ++nt) {
            bf16x8 bw1 = *(const bf16x8*)(&Wl[(nt * 16 + nm) * PITCH + ks * 32 + quad * 8]);
            acc[nt] = __builtin_amdgcn_mfma_f32_16x16x32_bf16(af1, bw1, acc[nt], 0, 0, 0);
            bf16x8 bw0 = *(const bf16x8*)(&Wl[128 * PITCH + (nt * 16 + nm) * PITCH + ks * 32 + quad * 8]);
            acc[nt] = __builtin_amdgcn_mfma_f32_16x16x32_bf16(af0, bw0, acc[nt], 0, 0, 0);
        }
    }
    unsigned short* orow = out + (size_t)(row0 + quad * 4) * 128 + nm;
#pragma unroll
    for (int nt = 0; nt < 8; ++nt) {
        float bb = b1[nt * 16 + nm] + b0[nt * 16 + nm];
#pragma unroll
        for (int r = 0; r < 4; ++r)
            orow[(size_t)r * 128 + nt * 16] = packbf1(acc[nt][r] + bb);
    }
}

// ---------------------------------------------------------------------------
// Dual SPMM from one gather table: out1 = A1 (x) g ; out0 = A0 (x) g
// wave per row; lane l owns cols 2l,2l+1 (one u32 per edge per lane).
// ---------------------------------------------------------------------------
__global__ __launch_bounds__(256) void spmm_dual(
    const int* __restrict__ rp1, const int2* __restrict__ cv1,
    const int* __restrict__ rp0, const int2* __restrict__ cv0,
    const unsigned short* __restrict__ g,
    unsigned short* __restrict__ out1, unsigned short* __restrict__ out0, int nrows) {
    const int wave = (blockIdx.x * 256 + threadIdx.x) >> 6;
    const int lane = threadIdx.x & 63;
    if (wave >= nrows) return;
    const int r = wave;
    const int col2 = lane * 2;
    float a1lo = 0.f, a1hi = 0.f, a0lo = 0.f, a0hi = 0.f;

    {
        int e = rp1[r], eend = rp1[r + 1];
        for (; e + 4 <= eend; e += 4) {
            int2 ea = cv1[e], eb = cv1[e + 1], ec = cv1[e + 2], ed = cv1[e + 3];
            unsigned ua = *(const unsigned*)&g[(ea.x << 7) + col2];
            unsigned ub = *(const unsigned*)&g[(eb.x << 7) + col2];
            unsigned uc = *(const unsigned*)&g[(ec.x << 7) + col2];
            unsigned ud = *(const unsigned*)&g[(ed.x << 7) + col2];
            float va = __int_as_float(ea.y), vb = __int_as_float(eb.y);
            float vc = __int_as_float(ec.y), vd = __int_as_float(ed.y);
            a1lo += va * bf_lo(ua) + vb * bf_lo(ub) + vc * bf_lo(uc) + vd * bf_lo(ud);
            a1hi += va * bf_hi(ua) + vb * bf_hi(ub) + vc * bf_hi(uc) + vd * bf_hi(ud);
        }
        for (; e < eend; ++e) {
            int2 ea = cv1[e];
            unsigned ua = *(const unsigned*)&g[(ea.x << 7) + col2];
            float va = __int_as_float(ea.y);
            a1lo += va * bf_lo(ua);
            a1hi += va * bf_hi(ua);
        }
    }
    {
        int e = rp0[r], eend = rp0[r + 1];
        for (; e + 4 <= eend; e += 4) {
            int2 ea = cv0[e], eb = cv0[e + 1], ec = cv0[e + 2], ed = cv0[e + 3];
            unsigned ua = *(const unsigned*)&g[(ea.x << 7) + col2];
            unsigned ub = *(const unsigned*)&g[(eb.x << 7) + col2];
            unsigned uc = *(const unsigned*)&g[(ec.x << 7) + col2];
            unsigned ud = *(const unsigned*)&g[(ed.x << 7) + col2];
            float va = __int_as_float(ea.y), vb = __int_as_float(eb.y);
            float vc = __int_as_float(ec.y), vd = __int_as_float(ed.y);
            a0lo += va * bf_lo(ua) + vb * bf_lo(ub) + vc * bf_lo(uc) + vd * bf_lo(ud);
            a0hi += va * bf_hi(ua) + vb * bf_hi(ub) + vc * bf_hi(uc) + vd * bf_hi(ud);
        }
        for (; e < eend; ++e) {
            int2 ea = cv0[e];
            unsigned ua = *(const unsigned*)&g[(ea.x << 7) + col2];
            float va = __int_as_float(ea.y);
            a0lo += va * bf_lo(ua);
            a0hi += va * bf_hi(ua);
        }
    }
    const int base = r << 7;
    *(unsigned*)&out1[base + col2] = packbf2(a1lo, a1hi);
    *(unsigned*)&out0[base + col2] = packbf2(a0lo, a0hi);
}

// ---------------------------------------------------------------------------
// fp32 tiled GEMM for the head: out = act( X @ |W|^T + b )
// ---------------------------------------------------------------------------
template <int KK, int NCOLS, int ROWS, bool ABSW, bool SIG>
__global__ __launch_bounds__(256) void gemm_xwT(const float* __restrict__ X,
                                                const float* __restrict__ W,
                                                const float* __restrict__ bias,
                                                float* __restrict__ out, int M) {
    constexpr int KP = 32;
    constexpr int NG = 256 / NCOLS;
    constexpr int RT = ROWS / NG;
    __shared__ float BT[KP * (NCOLS + 1)];
    __shared__ float Xl[ROWS * (KK + 1)];
    const int t = threadIdx.x;
    const int j = t % NCOLS;
    const int rg = t / NCOLS;
    const int row0 = blockIdx.x * ROWS;

    for (int idx = t; idx < ROWS * KK; idx += 256) {
        int r = idx / KK, k = idx % KK;
        int gr = row0 + r;
        Xl[r * (KK + 1) + k] = (gr < M) ? X[gr * KK + k] : 0.f;
    }
    float acc[RT];
#pragma unroll
    for (int i = 0; i < RT; ++i) acc[i] = 0.f;

    for (int k0 = 0; k0 < KK; k0 += KP) {
        __syncthreads();
        for (int idx = t; idx < NCOLS * KP; idx += 256) {
            int jj = idx / KP, kp = idx % KP;
            float w = W[jj * KK + k0 + kp];
            BT[kp * (NCOLS + 1) + jj] = ABSW ? fabsf(w) : w;
        }
        __syncthreads();
#pragma unroll
        for (int kp = 0; kp < KP; ++kp) {
            float b = BT[kp * (NCOLS + 1) + j];
#pragma unroll
            for (int rr = 0; rr < RT; ++rr)
                acc[rr] += Xl[(rg * RT + rr) * (KK + 1) + k0 + kp] * b;
        }
    }
    float bj = bias ? bias[j] : 0.f;
#pragma unroll
    for (int rr = 0; rr < RT; ++rr) {
        int gr = row0 + rg * RT + rr;
        if (gr < M) {
            float v = acc[rr] + bj;
            out[gr * NCOLS + j] = SIG ? sigmoidf_(v) : v;
        }
    }
}

// ---------------------------------------------------------------------------
// Head kernels
// ---------------------------------------------------------------------------
__global__ __launch_bounds__(128) void head1_kernel(
    const int* __restrict__ stu_id, const int* __restrict__ exer_id,
    const float* __restrict__ kn_emb, const unsigned short* __restrict__ stat,
    const unsigned short* __restrict__ kdiff, const float* __restrict__ stu_bias,
    const float* __restrict__ e_disc, float* __restrict__ x) {
    const int b = blockIdx.x;
    const int k = threadIdx.x;
    const int sid = stu_id[b], eid = exer_id[b];
    float disc = sigmoidf_(e_disc[eid]);
    float sb = sigmoidf_(bf_one(stat[(sid << 7) + k]) + stu_bias[sid]);
    float kd = sigmoidf_(bf_one(kdiff[(eid << 7) + k]));
    x[(b << 7) + k] = disc * (sb - kd) * kn_emb[(b << 7) + k];
}

__global__ __launch_bounds__(256) void pn3_kernel(const float* __restrict__ h2,
                                                  const float* __restrict__ w3,
                                                  const float* __restrict__ b3,
                                                  float* __restrict__ out) {
    __shared__ float wl[128];
    const int t = threadIdx.x;
    if (t < 128) wl[t] = fabsf(w3[t]);
    __syncthreads();
    const int b = blockIdx.x * 256 + t;
    float acc = 0.f;
#pragma unroll 4
    for (int k = 0; k < 128; ++k) acc += h2[(b << 7) + k] * wl[k];
    out[b] = sigmoidf_(acc + b3[0]);
}

// ---------------------------------------------------------------------------
// Launch
// ---------------------------------------------------------------------------
static inline size_t align256(size_t x) { return (x + 255) & ~size_t(255); }

extern "C" void kernel_launch(void* const* d_in, const int* in_sizes, int n_in,
                              void* d_out, int out_size, void* d_ws, size_t ws_size,
                              hipStream_t stream) {
    const int*   stu_id   = (const int*)d_in[0];
    const int*   exer_id  = (const int*)d_in[1];
    const float* kn_emb   = (const float*)d_in[2];
    const float* stu_emb  = (const float*)d_in[3];
    const float* exer_emb = (const float*)d_in[4];
    const float* kn_base  = (const float*)d_in[5];
    const float* stu_bias = (const float*)d_in[6];
    const float* e_disc   = (const float*)d_in[7];
    const float* W1_w     = (const float*)d_in[8];
    const float* W1_b     = (const float*)d_in[9];
    const float* W0_w     = (const float*)d_in[10];
    const float* W0_b     = (const float*)d_in[11];
    const float* pn1_w    = (const float*)d_in[12];
    const float* pn1_b    = (const float*)d_in[13];
    const float* pn2_w    = (const float*)d_in[14];
    const float* pn2_b    = (const float*)d_in[15];
    const float* pn3_w    = (const float*)d_in[16];
    const float* pn3_b    = (const float*)d_in[17];
    const int*   ui1_r = (const int*)d_in[18]; const int* ui1_c = (const int*)d_in[19];
    const float* ui1_v = (const float*)d_in[20];
    const int*   iu1_r = (const int*)d_in[21]; const int* iu1_c = (const int*)d_in[22];
    const float* iu1_v = (const float*)d_in[23];
    const int*   ui0_r = (const int*)d_in[24]; const int* ui0_c = (const int*)d_in[25];
    const float* ui0_v = (const float*)d_in[26];
    const int*   iu0_r = (const int*)d_in[27]; const int* iu0_c = (const int*)d_in[28];
    const float* iu0_v = (const float*)d_in[29];
    const float* d_i_1 = (const float*)d_in[30];
    const float* d_j_1 = (const float*)d_in[31];
    const float* d_i_0 = (const float*)d_in[32];
    const float* d_j_0 = (const float*)d_in[33];
    float* out = (float*)d_out;

    typedef unsigned short u16;
    char* p = (char*)d_ws;
    size_t off = 0;
    auto alloc = [&](size_t bytes) { char* q = p + off; off += align256(bytes); return q; };
    // bf16 state
    u16* stat  = (u16*)alloc(size_t(SN) * KN * 2);
    u16* kdiff = (u16*)alloc(size_t(EN) * KN * 2);
    // aggregation buffers
    u16* as1 = (u16*)alloc(size_t(SN) * KN * 2);
    u16* as0 = (u16*)alloc(size_t(SN) * KN * 2);
    u16* ae1 = (u16*)alloc(size_t(EN) * KN * 2);
    u16* ae0 = (u16*)alloc(size_t(EN) * KN * 2);
    // bf16 copies of inputs
    u16* Xs  = (u16*)alloc(size_t(SN) * DN * 2);
    u16* Xe  = (u16*)alloc(size_t(EN) * DN * 2);
    u16* Kb  = (u16*)alloc(size_t(KN) * DN * 2);
    u16* Wb1 = (u16*)alloc(size_t(KN) * KN * 2);
    u16* Wb0 = (u16*)alloc(size_t(KN) * KN * 2);
    // CSR
    int*  cnt_all = (int*)alloc(size_t(2 * SN + 2 * EN) * 4);
    int*  cur_all = (int*)alloc(size_t(2 * SN + 2 * EN) * 4);
    int*  rp_ui1 = (int*)alloc((SN + 1) * 4);
    int*  rp_ui0 = (int*)alloc((SN + 1) * 4);
    int*  rp_iu1 = (int*)alloc((EN + 1) * 4);
    int*  rp_iu0 = (int*)alloc((EN + 1) * 4);
    int2* cv_ui1 = (int2*)alloc(size_t(NE) * 8);
    int2* cv_ui0 = (int2*)alloc(size_t(NE) * 8);
    int2* cv_iu1 = (int2*)alloc(size_t(NE) * 8);
    int2* cv_iu0 = (int2*)alloc(size_t(NE) * 8);
    // head
    float* xh = (float*)alloc(size_t(BN) * KN * 4);
    float* h1 = (float*)alloc(size_t(BN) * 256 * 4);
    float* h2 = (float*)alloc(size_t(BN) * 128 * 4);
    if (off > ws_size) return;

    // ---- CSR build ----
    Csr4 c;
    c.rows[0] = ui1_r; c.cols[0] = ui1_c; c.vals[0] = ui1_v;
    c.rows[1] = ui0_r; c.cols[1] = ui0_c; c.vals[1] = ui0_v;
    c.rows[2] = iu1_r; c.cols[2] = iu1_c; c.vals[2] = iu1_v;
    c.rows[3] = iu0_r; c.cols[3] = iu0_c; c.vals[3] = iu0_v;
    c.cnt[0] = cnt_all;          c.cur[0] = cur_all;
    c.cnt[1] = cnt_all + SN;     c.cur[1] = cur_all + SN;
    c.cnt[2] = cnt_all + 2 * SN; c.cur[2] = cur_all + 2 * SN;
    c.cnt[3] = cnt_all + 2 * SN + EN; c.cur[3] = cur_all + 2 * SN + EN;
    c.rp[0] = rp_ui1; c.rp[1] = rp_ui0; c.rp[2] = rp_iu1; c.rp[3] = rp_iu0;
    c.cv[0] = cv_ui1; c.cv[1] = cv_ui0; c.cv[2] = cv_iu1; c.cv[3] = cv_iu0;
    c.n[0] = SN; c.n[1] = SN; c.n[2] = EN; c.n[3] = EN;

    hipMemsetAsync(cnt_all, 0, size_t(2 * SN + 2 * EN) * 4, stream);
    count_all<<<4 * EGRID, 256, 0, stream>>>(c);
    exscan_all<<<4, 1024, 0, stream>>>(c);
    fill_all<<<4 * EGRID, 256, 0, stream>>>(c);

    // ---- fp32 -> bf16 conversions ----
    f2bf<<<(SN * DN / 2 + 255) / 256, 256, 0, stream>>>(stu_emb, Xs, SN * DN / 2);
    f2bf<<<(EN * DN / 2 + 255) / 256, 256, 0, stream>>>(exer_emb, Xe, EN * DN / 2);
    f2bf<<<(KN * DN / 2 + 255) / 256, 256, 0, stream>>>(kn_base, Kb, KN * DN / 2);
    f2bf<<<(KN * KN / 2 + 255) / 256, 256, 0, stream>>>(W1_w, Wb1, KN * KN / 2);
    f2bf<<<(KN * KN / 2 + 255) / 256, 256, 0, stream>>>(W0_w, Wb0, KN * KN / 2);

    // ---- projections ----
    gemm_mfma<DN><<<(SN + 63) / 64, 256, 0, stream>>>(Xs, Kb, stat, SN);
    gemm_mfma<DN><<<(EN + 63) / 64, 256, 0, stream>>>(Xe, Kb, kdiff, EN);

    // ---- GCN layers: aggregate from state, then dual-weight projection ----
    for (int l = 0; l < NLAYER; ++l) {
        spmm_dual<<<(SN + 3) / 4, 256, 0, stream>>>(
            rp_ui1, cv_ui1, rp_ui0, cv_ui0, kdiff, as1, as0, SN);
        spmm_dual<<<(EN + 3) / 4, 256, 0, stream>>>(
            rp_iu1, cv_iu1, rp_iu0, cv_iu0, stat, ae1, ae0, EN);
        gemm2_mfma<<<(SN + 63) / 64, 256, 0, stream>>>(
            as1, as0, stat, d_i_1, d_i_0, Wb1, Wb0, W1_b, W0_b, stat, SN);
        gemm2_mfma<<<(EN + 63) / 64, 256, 0, stream>>>(
            ae1, ae0, kdiff, d_j_1, d_j_0, Wb1, Wb0, W1_b, W0_b, kdiff, EN);
    }

    // ---- head ----
    head1_kernel<<<BN, 128, 0, stream>>>(stu_id, exer_id, kn_emb, stat, kdiff,
                                         stu_bias, e_disc, xh);
    gemm_xwT<128, 256, 16, true, true><<<BN / 16, 256, 0, stream>>>(xh, pn1_w, pn1_b, h1, BN);
    gemm_xwT<256, 128, 32, true, true><<<BN / 32, 256, 0, stream>>>(h1, pn2_w, pn2_b, h2, BN);
    pn3_kernel<<<BN / 256, 256, 0, stream>>>(h2, pn3_w, pn3_b, out);
    (void)out_size; (void)n_in; (void)in_sizes;
}

// Round 4
// 1198.938 us; speedup vs baseline: 2.1399x; 1.1031x over previous
//
#include <hip/hip_runtime.h>
#include <hip/hip_bf16.h>

// Problem constants (from reference)
#define SN 50000
#define EN 20000
#define KN 128
#define DN 64
#define BN 4096
#define NE 1000000
#define NLAYER 3
#define EGRID ((NE + 255) / 256)

// Column-chunk bucketing: chunk = 4096 gather-table rows = 1MB bf16 (L2-resident)
#define CH_SHIFT 12
#define NCH0 5                    // side0 (ui): cols index kdiff, EN=20000 -> 5 chunks
#define NCH1 13                   // side1 (iu): cols index stat,  SN=50000 -> 13 chunks
#define SIDE1_BASE (SN * NCH0)    // 250000
#define NTOT (SN * NCH0 + EN * NCH1)  // 510000
#define NTILES ((NTOT + 1023) / 1024) // 499

typedef float f32x4 __attribute__((ext_vector_type(4)));
typedef short bf16x8 __attribute__((ext_vector_type(8)));

__device__ __forceinline__ float sigmoidf_(float v) { return 1.f / (1.f + __expf(-v)); }
__device__ __forceinline__ float bf_lo(unsigned u) { return __uint_as_float(u << 16); }
__device__ __forceinline__ float bf_hi(unsigned u) { return __uint_as_float(u & 0xffff0000u); }
__device__ __forceinline__ float bf_one(unsigned short s) { return __uint_as_float((unsigned)s << 16); }
__device__ __forceinline__ unsigned packbf2(float a, float b) {
    __hip_bfloat16 ha = __float2bfloat16(a), hb = __float2bfloat16(b);
    unsigned short ua = *(unsigned short*)&ha, ub = *(unsigned short*)&hb;
    return (unsigned)ua | ((unsigned)ub << 16);
}
__device__ __forceinline__ unsigned short packbf1(float a) {
    __hip_bfloat16 ha = __float2bfloat16(a);
    return *(unsigned short*)&ha;
}

// ---------------------------------------------------------------------------
// CSR build: per side, merged adjacency list counting-sorted by (row, chunk).
// Edge record int2: .x = col | (tag<<16)  (tag=1: pos adjacency), .y = val bits
// ---------------------------------------------------------------------------
struct CsrB {
    const int* rows[4]; const int* cols[4]; const float* vals[4];
    int* cnt; int* cur; int2* cv;
};

__device__ __forceinline__ int bucket_idx(int a, int r, int c) {
    int side = a >> 1;
    int nch = side ? NCH1 : NCH0;
    int base = side ? SIDE1_BASE : 0;
    return base + r * nch + (c >> CH_SHIFT);
}

__global__ __launch_bounds__(256) void count_all(CsrB c) {
    int a = blockIdx.x / EGRID;
    int i = (blockIdx.x - a * EGRID) * 256 + threadIdx.x;
    if (i < NE) atomicAdd(&c.cnt[bucket_idx(a, c.rows[a][i], c.cols[a][i])], 1);
}

__global__ __launch_bounds__(256) void fill_all(CsrB c) {
    int a = blockIdx.x / EGRID;
    int i = (blockIdx.x - a * EGRID) * 256 + threadIdx.x;
    if (i < NE) {
        int cc = c.cols[a][i];
        int p = atomicAdd(&c.cur[bucket_idx(a, c.rows[a][i], cc)], 1);
        int tag = 1 - (a & 1);
        c.cv[p] = make_int2(cc | (tag << 16), __float_as_int(c.vals[a][i]));
    }
}

// ---- coalesced 3-phase exclusive scan over the concatenated count array ----
__global__ __launch_bounds__(256) void scan_part(const int* __restrict__ cnt,
                                                 int* __restrict__ bsum) {
    __shared__ int red[256];
    int b = blockIdx.x, t = threadIdx.x;
    int i = b * 1024 + t * 4;
    int s = 0;
#pragma unroll
    for (int k = 0; k < 4; ++k) { int j = i + k; if (j < NTOT) s += cnt[j]; }
    red[t] = s; __syncthreads();
    for (int o = 128; o > 0; o >>= 1) { if (t < o) red[t] += red[t + o]; __syncthreads(); }
    if (t == 0) bsum[b] = red[0];
}

__global__ __launch_bounds__(512) void scan_top(int* __restrict__ bsum) {
    __shared__ int sh[512];
    int t = threadIdx.x;
    sh[t] = (t < NTILES) ? bsum[t] : 0;
    __syncthreads();
    for (int o = 1; o < 512; o <<= 1) {
        int v = sh[t]; int u = (t >= o) ? sh[t - o] : 0; __syncthreads();
        sh[t] = v + u; __syncthreads();
    }
    if (t < NTILES) bsum[t] = (t == 0) ? 0 : sh[t - 1];
    if (t == 0) bsum[NTILES] = sh[511];
}

__global__ __launch_bounds__(256) void scan_fin(const int* __restrict__ cnt,
                                                const int* __restrict__ bsum,
                                                int* __restrict__ rp, int* __restrict__ cur) {
    __shared__ int sh[256];
    int b = blockIdx.x, t = threadIdx.x;
    int i = b * 1024 + t * 4;
    int v[4]; int s = 0;
#pragma unroll
    for (int k = 0; k < 4; ++k) { int j = i + k; v[k] = (j < NTOT) ? cnt[j] : 0; s += v[k]; }
    sh[t] = s; __syncthreads();
    for (int o = 1; o < 256; o <<= 1) {
        int x = sh[t]; int u = (t >= o) ? sh[t - o] : 0; __syncthreads();
        sh[t] = x + u; __syncthreads();
    }
    int pre = bsum[b] + ((t == 0) ? 0 : sh[t - 1]);
#pragma unroll
    for (int k = 0; k < 4; ++k) {
        int j = i + k;
        if (j < NTOT) { rp[j] = pre; cur[j] = pre; pre += v[k]; }
    }
    if (b == 0 && t == 0) rp[NTOT] = bsum[NTILES];
}

// ---------------------------------------------------------------------------
// fp32 -> bf16 conversion (small weight tables only)
// ---------------------------------------------------------------------------
__global__ __launch_bounds__(256) void f2bf(const float* __restrict__ src,
                                            unsigned short* __restrict__ dst, int n2) {
    int i = blockIdx.x * 256 + threadIdx.x;
    if (i < n2) {
        float2 f = ((const float2*)src)[i];
        ((unsigned*)dst)[i] = packbf2(f.x, f.y);
    }
}

// ---------------------------------------------------------------------------
// Projection MFMA GEMM: out[M,128](bf16) = X[M,KK](f32, converted) @ W[128,KK]^T(bf16)
// ---------------------------------------------------------------------------
template <int KK>
__global__ __launch_bounds__(256) void gemm_proj(const float* __restrict__ X,
                                                 const unsigned short* __restrict__ W,
                                                 unsigned short* __restrict__ out, int M) {
    constexpr int PITCH = KK + 8;
    __shared__ unsigned short Wl[128 * PITCH];
    const int t = threadIdx.x;
    for (int idx = t * 8; idx < 128 * KK; idx += 2048) {
        int r = idx / KK, k = idx - r * KK;
        *(uint4*)(&Wl[r * PITCH + k]) = *(const uint4*)(&W[idx]);
    }
    __syncthreads();
    const int lane = t & 63;
    const int nm = lane & 15;
    const int quad = lane >> 4;
    const int row0 = blockIdx.x * 64 + (t >> 6) * 16;
    if (row0 >= M) return;

    f32x4 acc[8];
#pragma unroll
    for (int nt = 0; nt < 8; ++nt) acc[nt] = (f32x4){0.f, 0.f, 0.f, 0.f};

    const float* xrow = X + (size_t)(row0 + nm) * KK + quad * 8;
#pragma unroll
    for (int ks = 0; ks < KK / 32; ++ks) {
        float4 f0 = *(const float4*)(xrow + ks * 32);
        float4 f1 = *(const float4*)(xrow + ks * 32 + 4);
        unsigned q[4] = {packbf2(f0.x, f0.y), packbf2(f0.z, f0.w),
                         packbf2(f1.x, f1.y), packbf2(f1.z, f1.w)};
        bf16x8 a = *(bf16x8*)q;
#pragma unroll
        for (int nt = 0; nt < 8; ++nt) {
            bf16x8 b = *(const bf16x8*)(&Wl[(nt * 16 + nm) * PITCH + ks * 32 + quad * 8]);
            acc[nt] = __builtin_amdgcn_mfma_f32_16x16x32_bf16(a, b, acc[nt], 0, 0, 0);
        }
    }
    unsigned short* orow = out + (size_t)(row0 + quad * 4) * 128 + nm;
#pragma unroll
    for (int r = 0; r < 4; ++r)
#pragma unroll
        for (int nt = 0; nt < 8; ++nt)
            orow[(size_t)r * 128 + nt * 16] = packbf1(acc[nt][r]);
}

// ---------------------------------------------------------------------------
// Fused dual-weight MFMA GEMM (one GCN layer side, in-place safe):
//   out = (agg1 + d1.*y)@W1^T + (agg0 + d0.*y)@W0^T + (b1+b0)
// ---------------------------------------------------------------------------
__global__ __launch_bounds__(256) void gemm2_mfma(
    const unsigned short* __restrict__ agg1, const unsigned short* __restrict__ agg0,
    const unsigned short* __restrict__ y,
    const float* __restrict__ d1, const float* __restrict__ d0,
    const unsigned short* __restrict__ W1, const unsigned short* __restrict__ W0,
    const float* __restrict__ b1, const float* __restrict__ b0,
    unsigned short* __restrict__ out, int M) {
    constexpr int PITCH = 136;
    __shared__ unsigned short Wl[2 * 128 * PITCH];
    const int t = threadIdx.x;
    for (int idx = t * 8; idx < 128 * 128; idx += 2048) {
        int r = idx >> 7, k = idx & 127;
        *(uint4*)(&Wl[r * PITCH + k]) = *(const uint4*)(&W1[idx]);
        *(uint4*)(&Wl[128 * PITCH + r * PITCH + k]) = *(const uint4*)(&W0[idx]);
    }
    __syncthreads();
    const int lane = t & 63;
    const int nm = lane & 15;
    const int quad = lane >> 4;
    const int row0 = blockIdx.x * 64 + (t >> 6) * 16;
    if (row0 >= M) return;

    const float d1v = d1[row0 + nm];
    const float d0v = d0[row0 + nm];

    f32x4 acc[8];
#pragma unroll
    for (int nt = 0; nt < 8; ++nt) acc[nt] = (f32x4){0.f, 0.f, 0.f, 0.f};

    const size_t rbase = (size_t)(row0 + nm) * 128 + quad * 8;
#pragma unroll
    for (int ks = 0; ks < 4; ++ks) {
        uint4 ua1 = *(const uint4*)(agg1 + rbase + ks * 32);
        uint4 ua0 = *(const uint4*)(agg0 + rbase + ks * 32);
        uint4 uy  = *(const uint4*)(y    + rbase + ks * 32);
        uint4 p1, p0;
        {
            unsigned* a1 = (unsigned*)&ua1; unsigned* a0 = (unsigned*)&ua0;
            unsigned* yy = (unsigned*)&uy;
            unsigned* q1 = (unsigned*)&p1; unsigned* q0 = (unsigned*)&p0;
#pragma unroll
            for (int w = 0; w < 4; ++w) {
                float ylo = bf_lo(yy[w]), yhi = bf_hi(yy[w]);
                q1[w] = packbf2(bf_lo(a1[w]) + d1v * ylo, bf_hi(a1[w]) + d1v * yhi);
                q0[w] = packbf2(bf_lo(a0[w]) + d0v * ylo, bf_hi(a0[w]) + d0v * yhi);
            }
        }
        bf16x8 af1 = *(bf16x8*)&p1;
        bf16x8 af0 = *(bf16x8*)&p0;
#pragma unroll
        for (int nt = 0; nt < 8; ++nt) {
            bf16x8 bw1 = *(const bf16x8*)(&Wl[(nt * 16 + nm) * PITCH + ks * 32 + quad * 8]);
            acc[nt] = __builtin_amdgcn_mfma_f32_16x16x32_bf16(af1, bw1, acc[nt], 0, 0, 0);
            bf16x8 bw0 = *(const bf16x8*)(&Wl[128 * PITCH + (nt * 16 + nm) * PITCH + ks * 32 + quad * 8]);
            acc[nt] = __builtin_amdgcn_mfma_f32_16x16x32_bf16(af0, bw0, acc[nt], 0, 0, 0);
        }
    }
    unsigned short* orow = out + (size_t)(row0 + quad * 4) * 128 + nm;
#pragma unroll
    for (int nt = 0; nt < 8; ++nt) {
        float bb = b1[nt * 16 + nm] + b0[nt * 16 + nm];
#pragma unroll
        for (int r = 0; r < 4; ++r)
            orow[(size_t)r * 128 + nt * 16] = packbf1(acc[nt][r] + bb);
    }
}

// ---------------------------------------------------------------------------
// Merged dual SPMM: one chunk-sorted edge list per row, adjacency tag in bit16.
// out1 = A1 (x) g ; out0 = A0 (x) g. Wave per row; lane owns cols 2l,2l+1.
// ---------------------------------------------------------------------------
__global__ __launch_bounds__(256) void spmm_dual(
    const int* __restrict__ rp, const int2* __restrict__ cv,
    const unsigned short* __restrict__ g,
    unsigned short* __restrict__ out1, unsigned short* __restrict__ out0,
    int nrows, int nch) {
    const int wave = (blockIdx.x * 256 + threadIdx.x) >> 6;
    const int lane = threadIdx.x & 63;
    if (wave >= nrows) return;
    const int r = wave;
    const int col2 = lane * 2;
    float a1lo = 0.f, a1hi = 0.f, a0lo = 0.f, a0hi = 0.f;

    int e = rp[r * nch], ee = rp[(r + 1) * nch];
#define EDGE(E, U)                                                     \
    {                                                                  \
        float v = __int_as_float((E).y);                               \
        bool t1 = ((E).x & 0x10000) != 0;                              \
        float v1 = t1 ? v : 0.f;                                       \
        float v0 = t1 ? 0.f : v;                                       \
        float glo = bf_lo(U), ghi = bf_hi(U);                          \
        a1lo += v1 * glo; a1hi += v1 * ghi;                            \
        a0lo += v0 * glo; a0hi += v0 * ghi;                            \
    }
    for (; e + 4 <= ee; e += 4) {
        int2 E0 = cv[e], E1 = cv[e + 1], E2 = cv[e + 2], E3 = cv[e + 3];
        unsigned u0 = *(const unsigned*)&g[((E0.x & 0xFFFF) << 7) + col2];
        unsigned u1 = *(const unsigned*)&g[((E1.x & 0xFFFF) << 7) + col2];
        unsigned u2 = *(const unsigned*)&g[((E2.x & 0xFFFF) << 7) + col2];
        unsigned u3 = *(const unsigned*)&g[((E3.x & 0xFFFF) << 7) + col2];
        EDGE(E0, u0) EDGE(E1, u1) EDGE(E2, u2) EDGE(E3, u3)
    }
    for (; e < ee; ++e) {
        int2 E0 = cv[e];
        unsigned u0 = *(const unsigned*)&g[((E0.x & 0xFFFF) << 7) + col2];
        EDGE(E0, u0)
    }
#undef EDGE
    const int base = r << 7;
    *(unsigned*)&out1[base + col2] = packbf2(a1lo, a1hi);
    *(unsigned*)&out0[base + col2] = packbf2(a0lo, a0hi);
}

// ---------------------------------------------------------------------------
// fp32 tiled GEMM for the head: out = act( X @ |W|^T + b )
// ---------------------------------------------------------------------------
template <int KK, int NCOLS, int ROWS, bool ABSW, bool SIG>
__global__ __launch_bounds__(256) void gemm_xwT(const float* __restrict__ X,
                                                const float* __restrict__ W,
                                                const float* __restrict__ bias,
                                                float* __restrict__ out, int M) {
    constexpr int KP = 32;
    constexpr int NG = 256 / NCOLS;
    constexpr int RT = ROWS / NG;
    __shared__ float BT[KP * (NCOLS + 1)];
    __shared__ float Xl[ROWS * (KK + 1)];
    const int t = threadIdx.x;
    const int j = t % NCOLS;
    const int rg = t / NCOLS;
    const int row0 = blockIdx.x * ROWS;

    for (int idx = t; idx < ROWS * KK; idx += 256) {
        int r = idx / KK, k = idx % KK;
        int gr = row0 + r;
        Xl[r * (KK + 1) + k] = (gr < M) ? X[gr * KK + k] : 0.f;
    }
    float acc[RT];
#pragma unroll
    for (int i = 0; i < RT; ++i) acc[i] = 0.f;

    for (int k0 = 0; k0 < KK; k0 += KP) {
        __syncthreads();
        for (int idx = t; idx < NCOLS * KP; idx += 256) {
            int jj = idx / KP, kp = idx % KP;
            float w = W[jj * KK + k0 + kp];
            BT[kp * (NCOLS + 1) + jj] = ABSW ? fabsf(w) : w;
        }
        __syncthreads();
#pragma unroll
        for (int kp = 0; kp < KP; ++kp) {
            float b = BT[kp * (NCOLS + 1) + j];
#pragma unroll
            for (int rr = 0; rr < RT; ++rr)
                acc[rr] += Xl[(rg * RT + rr) * (KK + 1) + k0 + kp] * b;
        }
    }
    float bj = bias ? bias[j] : 0.f;
#pragma unroll
    for (int rr = 0; rr < RT; ++rr) {
        int gr = row0 + rg * RT + rr;
        if (gr < M) {
            float v = acc[rr] + bj;
            out[gr * NCOLS + j] = SIG ? sigmoidf_(v) : v;
        }
    }
}

// ---------------------------------------------------------------------------
// Head kernels
// ---------------------------------------------------------------------------
__global__ __launch_bounds__(128) void head1_kernel(
    const int* __restrict__ stu_id, const int* __restrict__ exer_id,
    const float* __restrict__ kn_emb, const unsigned short* __restrict__ stat,
    const unsigned short* __restrict__ kdiff, const float* __restrict__ stu_bias,
    const float* __restrict__ e_disc, float* __restrict__ x) {
    const int b = blockIdx.x;
    const int k = threadIdx.x;
    const int sid = stu_id[b], eid = exer_id[b];
    float disc = sigmoidf_(e_disc[eid]);
    float sb = sigmoidf_(bf_one(stat[(sid << 7) + k]) + stu_bias[sid]);
    float kd = sigmoidf_(bf_one(kdiff[(eid << 7) + k]));
    x[(b << 7) + k] = disc * (sb - kd) * kn_emb[(b << 7) + k];
}

__global__ __launch_bounds__(256) void pn3_kernel(const float* __restrict__ h2,
                                                  const float* __restrict__ w3,
                                                  const float* __restrict__ b3,
                                                  float* __restrict__ out) {
    __shared__ float wl[128];
    const int t = threadIdx.x;
    if (t < 128) wl[t] = fabsf(w3[t]);
    __syncthreads();
    const int b = blockIdx.x * 256 + t;
    float acc = 0.f;
#pragma unroll 4
    for (int k = 0; k < 128; ++k) acc += h2[(b << 7) + k] * wl[k];
    out[b] = sigmoidf_(acc + b3[0]);
}

// ---------------------------------------------------------------------------
// Launch
// ---------------------------------------------------------------------------
static inline size_t align256(size_t x) { return (x + 255) & ~size_t(255); }

extern "C" void kernel_launch(void* const* d_in, const int* in_sizes, int n_in,
                              void* d_out, int out_size, void* d_ws, size_t ws_size,
                              hipStream_t stream) {
    const int*   stu_id   = (const int*)d_in[0];
    const int*   exer_id  = (const int*)d_in[1];
    const float* kn_emb   = (const float*)d_in[2];
    const float* stu_emb  = (const float*)d_in[3];
    const float* exer_emb = (const float*)d_in[4];
    const float* kn_base  = (const float*)d_in[5];
    const float* stu_bias = (const float*)d_in[6];
    const float* e_disc   = (const float*)d_in[7];
    const float* W1_w     = (const float*)d_in[8];
    const float* W1_b     = (const float*)d_in[9];
    const float* W0_w     = (const float*)d_in[10];
    const float* W0_b     = (const float*)d_in[11];
    const float* pn1_w    = (const float*)d_in[12];
    const float* pn1_b    = (const float*)d_in[13];
    const float* pn2_w    = (const float*)d_in[14];
    const float* pn2_b    = (const float*)d_in[15];
    const float* pn3_w    = (const float*)d_in[16];
    const float* pn3_b    = (const float*)d_in[17];
    const int*   ui1_r = (const int*)d_in[18]; const int* ui1_c = (const int*)d_in[19];
    const float* ui1_v = (const float*)d_in[20];
    const int*   iu1_r = (const int*)d_in[21]; const int* iu1_c = (const int*)d_in[22];
    const float* iu1_v = (const float*)d_in[23];
    const int*   ui0_r = (const int*)d_in[24]; const int* ui0_c = (const int*)d_in[25];
    const float* ui0_v = (const float*)d_in[26];
    const int*   iu0_r = (const int*)d_in[27]; const int* iu0_c = (const int*)d_in[28];
    const float* iu0_v = (const float*)d_in[29];
    const float* d_i_1 = (const float*)d_in[30];
    const float* d_j_1 = (const float*)d_in[31];
    const float* d_i_0 = (const float*)d_in[32];
    const float* d_j_0 = (const float*)d_in[33];
    float* out = (float*)d_out;

    typedef unsigned short u16;
    char* p = (char*)d_ws;
    size_t off = 0;
    auto alloc = [&](size_t bytes) { char* q = p + off; off += align256(bytes); return q; };
    // bf16 state
    u16* stat  = (u16*)alloc(size_t(SN) * KN * 2);
    u16* kdiff = (u16*)alloc(size_t(EN) * KN * 2);
    // aggregation buffers
    u16* as1 = (u16*)alloc(size_t(SN) * KN * 2);
    u16* as0 = (u16*)alloc(size_t(SN) * KN * 2);
    u16* ae1 = (u16*)alloc(size_t(EN) * KN * 2);
    u16* ae0 = (u16*)alloc(size_t(EN) * KN * 2);
    // bf16 weight tables
    u16* Kb  = (u16*)alloc(size_t(KN) * DN * 2);
    u16* Wb1 = (u16*)alloc(size_t(KN) * KN * 2);
    u16* Wb0 = (u16*)alloc(size_t(KN) * KN * 2);
    // CSR (concatenated sides)
    int*  cnt_all = (int*)alloc(size_t(NTOT) * 4);
    int*  cur_all = (int*)alloc(size_t(NTOT) * 4);
    int*  rp_all  = (int*)alloc(size_t(NTOT + 1) * 4);
    int*  bsum    = (int*)alloc(size_t(NTILES + 1) * 4);
    int2* cv_all  = (int2*)alloc(size_t(4) * NE * 8);
    // head
    float* xh = (float*)alloc(size_t(BN) * KN * 4);
    float* h1 = (float*)alloc(size_t(BN) * 256 * 4);
    float* h2 = (float*)alloc(size_t(BN) * 128 * 4);
    if (off > ws_size) return;

    // ---- CSR build: counting sort by (row, col-chunk), both adjacencies merged ----
    CsrB c;
    c.rows[0] = ui1_r; c.cols[0] = ui1_c; c.vals[0] = ui1_v;
    c.rows[1] = ui0_r; c.cols[1] = ui0_c; c.vals[1] = ui0_v;
    c.rows[2] = iu1_r; c.cols[2] = iu1_c; c.vals[2] = iu1_v;
    c.rows[3] = iu0_r; c.cols[3] = iu0_c; c.vals[3] = iu0_v;
    c.cnt = cnt_all; c.cur = cur_all; c.cv = cv_all;

    hipMemsetAsync(cnt_all, 0, size_t(NTOT) * 4, stream);
    count_all<<<4 * EGRID, 256, 0, stream>>>(c);
    scan_part<<<NTILES, 256, 0, stream>>>(cnt_all, bsum);
    scan_top<<<1, 512, 0, stream>>>(bsum);
    scan_fin<<<NTILES, 256, 0, stream>>>(cnt_all, bsum, rp_all, cur_all);
    fill_all<<<4 * EGRID, 256, 0, stream>>>(c);

    // ---- bf16 weight conversions ----
    f2bf<<<(KN * DN / 2 + 255) / 256, 256, 0, stream>>>(kn_base, Kb, KN * DN / 2);
    f2bf<<<(KN * KN / 2 + 255) / 256, 256, 0, stream>>>(W1_w, Wb1, KN * KN / 2);
    f2bf<<<(KN * KN / 2 + 255) / 256, 256, 0, stream>>>(W0_w, Wb0, KN * KN / 2);

    // ---- projections (read f32 embeddings directly) ----
    gemm_proj<DN><<<(SN + 63) / 64, 256, 0, stream>>>(stu_emb, Kb, stat, SN);
    gemm_proj<DN><<<(EN + 63) / 64, 256, 0, stream>>>(exer_emb, Kb, kdiff, EN);

    // ---- GCN layers: chunk-local aggregate, then dual-weight projection ----
    for (int l = 0; l < NLAYER; ++l) {
        spmm_dual<<<(SN + 3) / 4, 256, 0, stream>>>(
            rp_all, cv_all, kdiff, as1, as0, SN, NCH0);
        spmm_dual<<<(EN + 3) / 4, 256, 0, stream>>>(
            rp_all + SIDE1_BASE, cv_all, stat, ae1, ae0, EN, NCH1);
        gemm2_mfma<<<(SN + 63) / 64, 256, 0, stream>>>(
            as1, as0, stat, d_i_1, d_i_0, Wb1, Wb0, W1_b, W0_b, stat, SN);
        gemm2_mfma<<<(EN + 63) / 64, 256, 0, stream>>>(
            ae1, ae0, kdiff, d_j_1, d_j_0, Wb1, Wb0, W1_b, W0_b, kdiff, EN);
    }

    // ---- head ----
    head1_kernel<<<BN, 128, 0, stream>>>(stu_id, exer_id, kn_emb, stat, kdiff,
                                         stu_bias, e_disc, xh);
    gemm_xwT<128, 256, 16, true, true><<<BN / 16, 256, 0, stream>>>(xh, pn1_w, pn1_b, h1, BN);
    gemm_xwT<256, 128, 32, true, true><<<BN / 32, 256, 0, stream>>>(h1, pn2_w, pn2_b, h2, BN);
    pn3_kernel<<<BN / 256, 256, 0, stream>>>(h2, pn3_w, pn3_b, out);
    (void)out_size; (void)n_in; (void)in_sizes;
}

// Round 5
// 845.413 us; speedup vs baseline: 3.0347x; 1.4182x over previous
//
#include <hip/hip_runtime.h>
#include <hip/hip_bf16.h>

// Problem constants (from reference)
#define SN 50000
#define EN 20000
#define KN 128
#define DN 64
#define BN 4096
#define NE 1000000
#define NLAYER 3

// Column-chunk bucketing: chunk = 4096 gather-table rows = 1MB bf16 (L2-resident)
#define CH_SHIFT 12
#define NCH0 5                        // side0 (ui): cols index kdiff, EN -> 5 chunks
#define NCH1 13                       // side1 (iu): cols index stat,  SN -> 13 chunks
#define SIDE1_BASE (SN * NCH0)        // 250000
#define NTOT (SN * NCH0 + EN * NCH1)  // 510000 fine buckets

// Two-pass partition sort
#define BIN_SHIFT 11
#define NBIN ((NTOT + 2047) >> 11)    // 250 coarse bins (2048 fine buckets each)
#define T1 4096                       // edges per part1 tile
#define PG1 ((NE + T1 - 1) / T1)      // 245 tiles per adjacency
#define HB 256                        // hist blocks per adjacency

typedef float f32x4 __attribute__((ext_vector_type(4)));
typedef short bf16x8 __attribute__((ext_vector_type(8)));

__device__ __forceinline__ float sigmoidf_(float v) { return 1.f / (1.f + __expf(-v)); }
__device__ __forceinline__ float bf_lo(unsigned u) { return __uint_as_float(u << 16); }
__device__ __forceinline__ float bf_hi(unsigned u) { return __uint_as_float(u & 0xffff0000u); }
__device__ __forceinline__ float bf_one(unsigned short s) { return __uint_as_float((unsigned)s << 16); }
__device__ __forceinline__ unsigned packbf2(float a, float b) {
    __hip_bfloat16 ha = __float2bfloat16(a), hb = __float2bfloat16(b);
    unsigned short ua = *(unsigned short*)&ha, ub = *(unsigned short*)&hb;
    return (unsigned)ua | ((unsigned)ub << 16);
}
__device__ __forceinline__ unsigned short packbf1(float a) {
    __hip_bfloat16 ha = __float2bfloat16(a);
    return *(unsigned short*)&ha;
}

struct CsrB {
    const int* rows[4]; const int* cols[4]; const float* vals[4];
};

// ---------------------------------------------------------------------------
// Coarse histogram (250 bins), LDS-staged
// ---------------------------------------------------------------------------
__global__ __launch_bounds__(256) void hist_coarse(CsrB c, int* __restrict__ cnt) {
    __shared__ int h[256];
    const int t = threadIdx.x;
    h[t] = 0;
    __syncthreads();
    const int a = blockIdx.x >> 8;
    const int tile = blockIdx.x & 255;
    const int per = (NE + HB - 1) / HB;
    const int beg = tile * per, end = min(beg + per, NE);
    const int side = a >> 1;
    const int nch = side ? NCH1 : NCH0;
    const int basebk = side ? SIDE1_BASE : 0;
    for (int i = beg + t; i < end; i += 256) {
        int B = basebk + c.rows[a][i] * nch + (c.cols[a][i] >> CH_SHIFT);
        atomicAdd(&h[B >> BIN_SHIFT], 1);
    }
    __syncthreads();
    if (h[t]) atomicAdd(&cnt[t], h[t]);
}

// 1-block exclusive scan of 256 coarse counts -> base[257] and tails[256]
__global__ __launch_bounds__(256) void scan_coarse(const int* __restrict__ cnt,
                                                   int* __restrict__ base,
                                                   int* __restrict__ tails) {
    __shared__ int sh[256];
    const int t = threadIdx.x;
    const int v = cnt[t];
    sh[t] = v;
    __syncthreads();
    for (int o = 1; o < 256; o <<= 1) {
        int x = sh[t]; int u = (t >= o) ? sh[t - o] : 0;
        __syncthreads(); sh[t] = x + u; __syncthreads();
    }
    const int ex = sh[t] - v;
    base[t] = ex;
    tails[t] = ex;
    if (t == 255) base[256] = sh[255];
}

// ---------------------------------------------------------------------------
// part1: multisplit edges into coarse-bin segments with coalesced writes.
// Record int2: .x = col(0..15) | tag(16) | fine_bucket_low11(17..27), .y = f32 val
// ---------------------------------------------------------------------------
__global__ __launch_bounds__(512) void part1(CsrB c, int* __restrict__ tails,
                                             int2* __restrict__ stg) {
    __shared__ int2 srec[T1];
    __shared__ unsigned char sbin[T1];
    __shared__ int h[256], offs[256], gbase[256], sc[512];
    const int t = threadIdx.x;
    const int a = blockIdx.x / PG1;
    const int tile = blockIdx.x - a * PG1;
    const int beg = tile * T1;
    const int cnt = min(T1, NE - beg);
    if (t < 256) h[t] = 0;
    __syncthreads();

    int2 rec[8]; int rbin[8]; int rrank[8];
    const int side = a >> 1;
    const int nch = side ? NCH1 : NCH0;
    const int basebk = side ? SIDE1_BASE : 0;
    const int tag = 1 - (a & 1);
#pragma unroll
    for (int k = 0; k < 8; ++k) {
        int o = t + k * 512;
        if (o < cnt) {
            int i = beg + o;
            int cc = c.cols[a][i];
            int B = basebk + c.rows[a][i] * nch + (cc >> CH_SHIFT);
            int bin = B >> BIN_SHIFT;
            rec[k] = make_int2(cc | (tag << 16) | ((B & 2047) << 17),
                               __float_as_int(c.vals[a][i]));
            rbin[k] = bin;
            rrank[k] = atomicAdd(&h[bin], 1);
        } else {
            rbin[k] = -1;
        }
    }
    __syncthreads();
    // exclusive scan of h -> offs; reserve global space per bin
    sc[t] = (t < 256) ? h[t] : 0;
    __syncthreads();
    for (int o = 1; o < 256; o <<= 1) {
        int x = sc[t]; int u = (t >= o) ? sc[t - o] : 0;
        __syncthreads(); sc[t] = x + u; __syncthreads();
    }
    if (t < 256) {
        offs[t] = sc[t] - h[t];
        if (h[t] > 0) gbase[t] = atomicAdd(&tails[t], h[t]);
    }
    __syncthreads();
#pragma unroll
    for (int k = 0; k < 8; ++k) {
        if (rbin[k] >= 0) {
            int pos = offs[rbin[k]] + rrank[k];
            srec[pos] = rec[k];
            sbin[pos] = (unsigned char)rbin[k];
        }
    }
    __syncthreads();
    for (int idx = t; idx < cnt; idx += 512) {
        int b = sbin[idx];
        stg[gbase[b] + (idx - offs[b])] = srec[idx];
    }
}

// ---------------------------------------------------------------------------
// part2: one block per coarse bin. Builds fine histogram+prefix in LDS
// (producing rp_all), then scatters records into the bin's own ~128KB window.
// ---------------------------------------------------------------------------
__global__ __launch_bounds__(512) void part2(const int* __restrict__ coarseBase,
                                             const int2* __restrict__ stg,
                                             int* __restrict__ rp,
                                             int2* __restrict__ cv) {
    __shared__ int cnt2[2048];
    __shared__ int tsum[512];
    const int b = blockIdx.x;
    const int t = threadIdx.x;
    const int fineBase = b << BIN_SHIFT;
    const int nf = min(2048, NTOT - fineBase);
    const int segBeg = coarseBase[b];
    const int segEnd = coarseBase[b + 1];
    for (int i = t; i < 2048; i += 512) cnt2[i] = 0;
    __syncthreads();
    for (int e = segBeg + t; e < segEnd; e += 512)
        atomicAdd(&cnt2[stg[e].x >> 17], 1);
    __syncthreads();
    // exclusive scan of cnt2[2048] (512 threads x 4)
    const int i4 = t * 4;
    int v0 = cnt2[i4], v1 = cnt2[i4 + 1], v2 = cnt2[i4 + 2], v3 = cnt2[i4 + 3];
    tsum[t] = v0 + v1 + v2 + v3;
    __syncthreads();
    for (int o = 1; o < 512; o <<= 1) {
        int x = tsum[t]; int u = (t >= o) ? tsum[t - o] : 0;
        __syncthreads(); tsum[t] = x + u; __syncthreads();
    }
    const int pre = (t == 0) ? 0 : tsum[t - 1];
    const int p0 = pre, p1 = pre + v0, p2 = p1 + v1, p3 = p2 + v2;
    cnt2[i4] = p0; cnt2[i4 + 1] = p1; cnt2[i4 + 2] = p2; cnt2[i4 + 3] = p3;
    if (i4 + 0 < nf) rp[fineBase + i4 + 0] = segBeg + p0;
    if (i4 + 1 < nf) rp[fineBase + i4 + 1] = segBeg + p1;
    if (i4 + 2 < nf) rp[fineBase + i4 + 2] = segBeg + p2;
    if (i4 + 3 < nf) rp[fineBase + i4 + 3] = segBeg + p3;
    if (b == NBIN - 1 && t == 511) rp[NTOT] = segEnd;
    __syncthreads();
    for (int e = segBeg + t; e < segEnd; e += 512) {
        int2 r = stg[e];
        int pos = segBeg + atomicAdd(&cnt2[r.x >> 17], 1);
        cv[pos] = make_int2(r.x & 0x1FFFF, r.y);
    }
}

// ---------------------------------------------------------------------------
// fp32 -> bf16 conversion (small weight tables only)
// ---------------------------------------------------------------------------
__global__ __launch_bounds__(256) void f2bf(const float* __restrict__ src,
                                            unsigned short* __restrict__ dst, int n2) {
    int i = blockIdx.x * 256 + threadIdx.x;
    if (i < n2) {
        float2 f = ((const float2*)src)[i];
        ((unsigned*)dst)[i] = packbf2(f.x, f.y);
    }
}

// ---------------------------------------------------------------------------
// Projection MFMA GEMM: out[M,128](bf16) = X[M,KK](f32) @ W[128,KK]^T(bf16)
// ---------------------------------------------------------------------------
template <int KK>
__global__ __launch_bounds__(256) void gemm_proj(const float* __restrict__ X,
                                                 const unsigned short* __restrict__ W,
                                                 unsigned short* __restrict__ out, int M) {
    constexpr int PITCH = KK + 8;
    __shared__ unsigned short Wl[128 * PITCH];
    const int t = threadIdx.x;
    for (int idx = t * 8; idx < 128 * KK; idx += 2048) {
        int r = idx / KK, k = idx - r * KK;
        *(uint4*)(&Wl[r * PITCH + k]) = *(const uint4*)(&W[idx]);
    }
    __syncthreads();
    const int lane = t & 63;
    const int nm = lane & 15;
    const int quad = lane >> 4;
    const int row0 = blockIdx.x * 64 + (t >> 6) * 16;
    if (row0 >= M) return;

    f32x4 acc[8];
#pragma unroll
    for (int nt = 0; nt < 8; ++nt) acc[nt] = (f32x4){0.f, 0.f, 0.f, 0.f};

    const float* xrow = X + (size_t)(row0 + nm) * KK + quad * 8;
#pragma unroll
    for (int ks = 0; ks < KK / 32; ++ks) {
        float4 f0 = *(const float4*)(xrow + ks * 32);
        float4 f1 = *(const float4*)(xrow + ks * 32 + 4);
        unsigned q[4] = {packbf2(f0.x, f0.y), packbf2(f0.z, f0.w),
                         packbf2(f1.x, f1.y), packbf2(f1.z, f1.w)};
        bf16x8 a = *(bf16x8*)q;
#pragma unroll
        for (int nt = 0; nt < 8; ++nt) {
            bf16x8 b = *(const bf16x8*)(&Wl[(nt * 16 + nm) * PITCH + ks * 32 + quad * 8]);
            acc[nt] = __builtin_amdgcn_mfma_f32_16x16x32_bf16(a, b, acc[nt], 0, 0, 0);
        }
    }
    unsigned short* orow = out + (size_t)(row0 + quad * 4) * 128 + nm;
#pragma unroll
    for (int r = 0; r < 4; ++r)
#pragma unroll
        for (int nt = 0; nt < 8; ++nt)
            orow[(size_t)r * 128 + nt * 16] = packbf1(acc[nt][r]);
}

// ---------------------------------------------------------------------------
// Fused dual-weight MFMA GEMM (one GCN layer side, in-place safe):
//   out = (agg1 + d1.*y)@W1^T + (agg0 + d0.*y)@W0^T + (b1+b0)
// ---------------------------------------------------------------------------
__global__ __launch_bounds__(256) void gemm2_mfma(
    const unsigned short* __restrict__ agg1, const unsigned short* __restrict__ agg0,
    const unsigned short* __restrict__ y,
    const float* __restrict__ d1, const float* __restrict__ d0,
    const unsigned short* __restrict__ W1, const unsigned short* __restrict__ W0,
    const float* __restrict__ b1, const float* __restrict__ b0,
    unsigned short* __restrict__ out, int M) {
    constexpr int PITCH = 136;
    __shared__ unsigned short Wl[2 * 128 * PITCH];
    const int t = threadIdx.x;
    for (int idx = t * 8; idx < 128 * 128; idx += 2048) {
        int r = idx >> 7, k = idx & 127;
        *(uint4*)(&Wl[r * PITCH + k]) = *(const uint4*)(&W1[idx]);
        *(uint4*)(&Wl[128 * PITCH + r * PITCH + k]) = *(const uint4*)(&W0[idx]);
    }
    __syncthreads();
    const int lane = t & 63;
    const int nm = lane & 15;
    const int quad = lane >> 4;
    const int row0 = blockIdx.x * 64 + (t >> 6) * 16;
    if (row0 >= M) return;

    const float d1v = d1[row0 + nm];
    const float d0v = d0[row0 + nm];

    f32x4 acc[8];
#pragma unroll
    for (int nt = 0; nt < 8; ++nt) acc[nt] = (f32x4){0.f, 0.f, 0.f, 0.f};

    const size_t rbase = (size_t)(row0 + nm) * 128 + quad * 8;
#pragma unroll
    for (int ks = 0; ks < 4; ++ks) {
        uint4 ua1 = *(const uint4*)(agg1 + rbase + ks * 32);
        uint4 ua0 = *(const uint4*)(agg0 + rbase + ks * 32);
        uint4 uy  = *(const uint4*)(y    + rbase + ks * 32);
        uint4 p1, p0;
        {
            unsigned* a1 = (unsigned*)&ua1; unsigned* a0 = (unsigned*)&ua0;
            unsigned* yy = (unsigned*)&uy;
            unsigned* q1 = (unsigned*)&p1; unsigned* q0 = (unsigned*)&p0;
#pragma unroll
            for (int w = 0; w < 4; ++w) {
                float ylo = bf_lo(yy[w]), yhi = bf_hi(yy[w]);
                q1[w] = packbf2(bf_lo(a1[w]) + d1v * ylo, bf_hi(a1[w]) + d1v * yhi);
                q0[w] = packbf2(bf_lo(a0[w]) + d0v * ylo, bf_hi(a0[w]) + d0v * yhi);
            }
        }
        bf16x8 af1 = *(bf16x8*)&p1;
        bf16x8 af0 = *(bf16x8*)&p0;
#pragma unroll
        for (int nt = 0; nt < 8; ++nt) {
            bf16x8 bw1 = *(const bf16x8*)(&Wl[(nt * 16 + nm) * PITCH + ks * 32 + quad * 8]);
            acc[nt] = __builtin_amdgcn_mfma_f32_16x16x32_bf16(af1, bw1, acc[nt], 0, 0, 0);
            bf16x8 bw0 = *(const bf16x8*)(&Wl[128 * PITCH + (nt * 16 + nm) * PITCH + ks * 32 + quad * 8]);
            acc[nt] = __builtin_amdgcn_mfma_f32_16x16x32_bf16(af0, bw0, acc[nt], 0, 0, 0);
        }
    }
    unsigned short* orow = out + (size_t)(row0 + quad * 4) * 128 + nm;
#pragma unroll
    for (int nt = 0; nt < 8; ++nt) {
        float bb = b1[nt * 16 + nm] + b0[nt * 16 + nm];
#pragma unroll
        for (int r = 0; r < 4; ++r)
            orow[(size_t)r * 128 + nt * 16] = packbf1(acc[nt][r] + bb);
    }
}

// ---------------------------------------------------------------------------
// Merged dual SPMM: chunk-sorted edge list per row, adjacency tag in bit16.
// ---------------------------------------------------------------------------
__global__ __launch_bounds__(256) void spmm_dual(
    const int* __restrict__ rp, const int2* __restrict__ cv,
    const unsigned short* __restrict__ g,
    unsigned short* __restrict__ out1, unsigned short* __restrict__ out0,
    int nrows, int nch) {
    const int wave = (blockIdx.x * 256 + threadIdx.x) >> 6;
    const int lane = threadIdx.x & 63;
    if (wave >= nrows) return;
    const int r = wave;
    const int col2 = lane * 2;
    float a1lo = 0.f, a1hi = 0.f, a0lo = 0.f, a0hi = 0.f;

    int e = rp[r * nch], ee = rp[(r + 1) * nch];
#define EDGE(E, U)                                                     \
    {                                                                  \
        float v = __int_as_float((E).y);                               \
        bool t1 = ((E).x & 0x10000) != 0;                              \
        float v1 = t1 ? v : 0.f;                                       \
        float v0 = t1 ? 0.f : v;                                       \
        float glo = bf_lo(U), ghi = bf_hi(U);                          \
        a1lo += v1 * glo; a1hi += v1 * ghi;                            \
        a0lo += v0 * glo; a0hi += v0 * ghi;                            \
    }
    for (; e + 4 <= ee; e += 4) {
        int2 E0 = cv[e], E1 = cv[e + 1], E2 = cv[e + 2], E3 = cv[e + 3];
        unsigned u0 = *(const unsigned*)&g[((E0.x & 0xFFFF) << 7) + col2];
        unsigned u1 = *(const unsigned*)&g[((E1.x & 0xFFFF) << 7) + col2];
        unsigned u2 = *(const unsigned*)&g[((E2.x & 0xFFFF) << 7) + col2];
        unsigned u3 = *(const unsigned*)&g[((E3.x & 0xFFFF) << 7) + col2];
        EDGE(E0, u0) EDGE(E1, u1) EDGE(E2, u2) EDGE(E3, u3)
    }
    for (; e < ee; ++e) {
        int2 E0 = cv[e];
        unsigned u0 = *(const unsigned*)&g[((E0.x & 0xFFFF) << 7) + col2];
        EDGE(E0, u0)
    }
#undef EDGE
    const int base = r << 7;
    *(unsigned*)&out1[base + col2] = packbf2(a1lo, a1hi);
    *(unsigned*)&out0[base + col2] = packbf2(a0lo, a0hi);
}

// ---------------------------------------------------------------------------
// fp32 tiled GEMM for the head: out = act( X @ |W|^T + b )
// ---------------------------------------------------------------------------
template <int KK, int NCOLS, int ROWS, bool ABSW, bool SIG>
__global__ __launch_bounds__(256) void gemm_xwT(const float* __restrict__ X,
                                                const float* __restrict__ W,
                                                const float* __restrict__ bias,
                                                float* __restrict__ out, int M) {
    constexpr int KP = 32;
    constexpr int NG = 256 / NCOLS;
    constexpr int RT = ROWS / NG;
    __shared__ float BT[KP * (NCOLS + 1)];
    __shared__ float Xl[ROWS * (KK + 1)];
    const int t = threadIdx.x;
    const int j = t % NCOLS;
    const int rg = t / NCOLS;
    const int row0 = blockIdx.x * ROWS;

    for (int idx = t; idx < ROWS * KK; idx += 256) {
        int r = idx / KK, k = idx % KK;
        int gr = row0 + r;
        Xl[r * (KK + 1) + k] = (gr < M) ? X[gr * KK + k] : 0.f;
    }
    float acc[RT];
#pragma unroll
    for (int i = 0; i < RT; ++i) acc[i] = 0.f;

    for (int k0 = 0; k0 < KK; k0 += KP) {
        __syncthreads();
        for (int idx = t; idx < NCOLS * KP; idx += 256) {
            int jj = idx / KP, kp = idx % KP;
            float w = W[jj * KK + k0 + kp];
            BT[kp * (NCOLS + 1) + jj] = ABSW ? fabsf(w) : w;
        }
        __syncthreads();
#pragma unroll
        for (int kp = 0; kp < KP; ++kp) {
            float b = BT[kp * (NCOLS + 1) + j];
#pragma unroll
            for (int rr = 0; rr < RT; ++rr)
                acc[rr] += Xl[(rg * RT + rr) * (KK + 1) + k0 + kp] * b;
        }
    }
    float bj = bias ? bias[j] : 0.f;
#pragma unroll
    for (int rr = 0; rr < RT; ++rr) {
        int gr = row0 + rg * RT + rr;
        if (gr < M) {
            float v = acc[rr] + bj;
            out[gr * NCOLS + j] = SIG ? sigmoidf_(v) : v;
        }
    }
}

// ---------------------------------------------------------------------------
// Head kernels
// ---------------------------------------------------------------------------
__global__ __launch_bounds__(128) void head1_kernel(
    const int* __restrict__ stu_id, const int* __restrict__ exer_id,
    const float* __restrict__ kn_emb, const unsigned short* __restrict__ stat,
    const unsigned short* __restrict__ kdiff, const float* __restrict__ stu_bias,
    const float* __restrict__ e_disc, float* __restrict__ x) {
    const int b = blockIdx.x;
    const int k = threadIdx.x;
    const int sid = stu_id[b], eid = exer_id[b];
    float disc = sigmoidf_(e_disc[eid]);
    float sb = sigmoidf_(bf_one(stat[(sid << 7) + k]) + stu_bias[sid]);
    float kd = sigmoidf_(bf_one(kdiff[(eid << 7) + k]));
    x[(b << 7) + k] = disc * (sb - kd) * kn_emb[(b << 7) + k];
}

__global__ __launch_bounds__(256) void pn3_kernel(const float* __restrict__ h2,
                                                  const float* __restrict__ w3,
                                                  const float* __restrict__ b3,
                                                  float* __restrict__ out) {
    __shared__ float wl[128];
    const int t = threadIdx.x;
    if (t < 128) wl[t] = fabsf(w3[t]);
    __syncthreads();
    const int b = blockIdx.x * 256 + t;
    float acc = 0.f;
#pragma unroll 4
    for (int k = 0; k < 128; ++k) acc += h2[(b << 7) + k] * wl[k];
    out[b] = sigmoidf_(acc + b3[0]);
}

// ---------------------------------------------------------------------------
// Launch
// ---------------------------------------------------------------------------
static inline size_t align256(size_t x) { return (x + 255) & ~size_t(255); }

extern "C" void kernel_launch(void* const* d_in, const int* in_sizes, int n_in,
                              void* d_out, int out_size, void* d_ws, size_t ws_size,
                              hipStream_t stream) {
    const int*   stu_id   = (const int*)d_in[0];
    const int*   exer_id  = (const int*)d_in[1];
    const float* kn_emb   = (const float*)d_in[2];
    const float* stu_emb  = (const float*)d_in[3];
    const float* exer_emb = (const float*)d_in[4];
    const float* kn_base  = (const float*)d_in[5];
    const float* stu_bias = (const float*)d_in[6];
    const float* e_disc   = (const float*)d_in[7];
    const float* W1_w     = (const float*)d_in[8];
    const float* W1_b     = (const float*)d_in[9];
    const float* W0_w     = (const float*)d_in[10];
    const float* W0_b     = (const float*)d_in[11];
    const float* pn1_w    = (const float*)d_in[12];
    const float* pn1_b    = (const float*)d_in[13];
    const float* pn2_w    = (const float*)d_in[14];
    const float* pn2_b    = (const float*)d_in[15];
    const float* pn3_w    = (const float*)d_in[16];
    const float* pn3_b    = (const float*)d_in[17];
    const int*   ui1_r = (const int*)d_in[18]; const int* ui1_c = (const int*)d_in[19];
    const float* ui1_v = (const float*)d_in[20];
    const int*   iu1_r = (const int*)d_in[21]; const int* iu1_c = (const int*)d_in[22];
    const float* iu1_v = (const float*)d_in[23];
    const int*   ui0_r = (const int*)d_in[24]; const int* ui0_c = (const int*)d_in[25];
    const float* ui0_v = (const float*)d_in[26];
    const int*   iu0_r = (const int*)d_in[27]; const int* iu0_c = (const int*)d_in[28];
    const float* iu0_v = (const float*)d_in[29];
    const float* d_i_1 = (const float*)d_in[30];
    const float* d_j_1 = (const float*)d_in[31];
    const float* d_i_0 = (const float*)d_in[32];
    const float* d_j_0 = (const float*)d_in[33];
    float* out = (float*)d_out;

    typedef unsigned short u16;
    char* p = (char*)d_ws;
    size_t off = 0;
    auto alloc = [&](size_t bytes) { char* q = p + off; off += align256(bytes); return q; };
    // bf16 state
    u16* stat  = (u16*)alloc(size_t(SN) * KN * 2);
    u16* kdiff = (u16*)alloc(size_t(EN) * KN * 2);
    // aggregation buffers
    u16* as1 = (u16*)alloc(size_t(SN) * KN * 2);
    u16* as0 = (u16*)alloc(size_t(SN) * KN * 2);
    u16* ae1 = (u16*)alloc(size_t(EN) * KN * 2);
    u16* ae0 = (u16*)alloc(size_t(EN) * KN * 2);
    // bf16 weight tables
    u16* Kb  = (u16*)alloc(size_t(KN) * DN * 2);
    u16* Wb1 = (u16*)alloc(size_t(KN) * KN * 2);
    u16* Wb0 = (u16*)alloc(size_t(KN) * KN * 2);
    // sort structures
    int*  coarseCnt  = (int*)alloc(256 * 4);
    int*  coarseBase = (int*)alloc(257 * 4);
    int*  tails      = (int*)alloc(256 * 4);
    int*  rp_all     = (int*)alloc(size_t(NTOT + 1) * 4);
    int2* stg        = (int2*)alloc(size_t(4) * NE * 8);
    int2* cv_all     = (int2*)alloc(size_t(4) * NE * 8);
    // head
    float* xh = (float*)alloc(size_t(BN) * KN * 4);
    float* h1 = (float*)alloc(size_t(BN) * 256 * 4);
    float* h2 = (float*)alloc(size_t(BN) * 128 * 4);
    if (off > ws_size) return;

    CsrB c;
    c.rows[0] = ui1_r; c.cols[0] = ui1_c; c.vals[0] = ui1_v;
    c.rows[1] = ui0_r; c.cols[1] = ui0_c; c.vals[1] = ui0_v;
    c.rows[2] = iu1_r; c.cols[2] = iu1_c; c.vals[2] = iu1_v;
    c.rows[3] = iu0_r; c.cols[3] = iu0_c; c.vals[3] = iu0_v;

    // ---- two-pass partition sort ----
    hipMemsetAsync(coarseCnt, 0, 256 * 4, stream);
    hist_coarse<<<4 * HB, 256, 0, stream>>>(c, coarseCnt);
    scan_coarse<<<1, 256, 0, stream>>>(coarseCnt, coarseBase, tails);
    part1<<<4 * PG1, 512, 0, stream>>>(c, tails, stg);
    part2<<<NBIN, 512, 0, stream>>>(coarseBase, stg, rp_all, cv_all);

    // ---- bf16 weight conversions ----
    f2bf<<<(KN * DN / 2 + 255) / 256, 256, 0, stream>>>(kn_base, Kb, KN * DN / 2);
    f2bf<<<(KN * KN / 2 + 255) / 256, 256, 0, stream>>>(W1_w, Wb1, KN * KN / 2);
    f2bf<<<(KN * KN / 2 + 255) / 256, 256, 0, stream>>>(W0_w, Wb0, KN * KN / 2);

    // ---- projections (read f32 embeddings directly) ----
    gemm_proj<DN><<<(SN + 63) / 64, 256, 0, stream>>>(stu_emb, Kb, stat, SN);
    gemm_proj<DN><<<(EN + 63) / 64, 256, 0, stream>>>(exer_emb, Kb, kdiff, EN);

    // ---- GCN layers: chunk-local aggregate, then dual-weight projection ----
    for (int l = 0; l < NLAYER; ++l) {
        spmm_dual<<<(SN + 3) / 4, 256, 0, stream>>>(
            rp_all, cv_all, kdiff, as1, as0, SN, NCH0);
        spmm_dual<<<(EN + 3) / 4, 256, 0, stream>>>(
            rp_all + SIDE1_BASE, cv_all, stat, ae1, ae0, EN, NCH1);
        gemm2_mfma<<<(SN + 63) / 64, 256, 0, stream>>>(
            as1, as0, stat, d_i_1, d_i_0, Wb1, Wb0, W1_b, W0_b, stat, SN);
        gemm2_mfma<<<(EN + 63) / 64, 256, 0, stream>>>(
            ae1, ae0, kdiff, d_j_1, d_j_0, Wb1, Wb0, W1_b, W0_b, kdiff, EN);
    }

    // ---- head ----
    head1_kernel<<<BN, 128, 0, stream>>>(stu_id, exer_id, kn_emb, stat, kdiff,
                                         stu_bias, e_disc, xh);
    gemm_xwT<128, 256, 16, true, true><<<BN / 16, 256, 0, stream>>>(xh, pn1_w, pn1_b, h1, BN);
    gemm_xwT<256, 128, 32, true, true><<<BN / 32, 256, 0, stream>>>(h1, pn2_w, pn2_b, h2, BN);
    pn3_kernel<<<BN / 256, 256, 0, stream>>>(h2, pn3_w, pn3_b, out);
    (void)out_size; (void)n_in; (void)in_sizes;
}